// Round 4
// baseline (363.482 us; speedup 1.0000x reference)
//
#include <hip/hip_runtime.h>

// MultiHeadAttn fused block, MI355X/gfx950.
// Round 4: attn async staging (counted vmcnt(4) + 4 raw barriers/tile, no
// __syncthreads in loop), P packed via v_cvt_pk_bf16_f32 into subtiled Pt
// read back with ds_read_b64_tr_b16, mask preloaded to LDS once, setprio
// around MFMA clusters.

typedef __attribute__((ext_vector_type(4))) float f32x4;
typedef __attribute__((ext_vector_type(8))) short s16x8;
typedef __attribute__((ext_vector_type(4))) short s16x4;
typedef __attribute__((ext_vector_type(2))) unsigned int u32x2;

__device__ __forceinline__ unsigned short f2bf(float f) {
  union { float f; unsigned u; } x; x.f = f;
  unsigned r = x.u + 0x7fffu + ((x.u >> 16) & 1u);
  return (unsigned short)(r >> 16);
}
__device__ __forceinline__ float bf2f(unsigned short h) {
  union { unsigned u; float f; } x; x.u = ((unsigned)h) << 16;
  return x.f;
}

__device__ __forceinline__ void gload_lds16(const void* g, void* l) {
  __builtin_amdgcn_global_load_lds(
      (const __attribute__((address_space(1))) unsigned int*)g,
      (__attribute__((address_space(3))) unsigned int*)l, 16, 0, 0);
}

__device__ __forceinline__ unsigned lds_off(const void* p) {
  return (unsigned)(size_t)(const __attribute__((address_space(3))) void*)p;
}

__global__ __launch_bounds__(256) void cvt_f32_bf16(
    const float* __restrict__ src, unsigned short* __restrict__ dst, int n4) {
  int i = blockIdx.x * blockDim.x + threadIdx.x;
  if (i >= n4) return;
  float4 f = reinterpret_cast<const float4*>(src)[i];
  s16x4 o;
  o[0] = (short)f2bf(f.x); o[1] = (short)f2bf(f.y);
  o[2] = (short)f2bf(f.z); o[3] = (short)f2bf(f.w);
  reinterpret_cast<s16x4*>(dst)[i] = o;
}

// C[M,N] = A[M,K] @ B[N,K]^T, all bf16 (C bf16 out), optional bias+relu epilogue.
// 128x128 tile, BK=32, 4 waves (2x2), 4x4 16x16x32 frags per wave.
template<int RELU_BIAS>
__global__ __launch_bounds__(256) void gemm_bt(
    const unsigned short* __restrict__ A, const unsigned short* __restrict__ B,
    unsigned short* __restrict__ C, const float* __restrict__ bias,
    int M, int N, int K) {
  __shared__ __align__(16) unsigned short As[128 * 32];
  __shared__ __align__(16) unsigned short Bs[128 * 32];
  const int tid = threadIdx.x;
  const int lane = tid & 63;
  const int w = tid >> 6;
  const int brow = blockIdx.x * 128;
  const int bcol = blockIdx.y * 128;
  const int wr = (w >> 1) * 64;
  const int wc = (w & 1) * 64;

  f32x4 acc[4][4] = {};

  const int srow = w * 32 + (lane >> 2);  // + j*16
  const int scol = (lane & 3) * 8;
  const int rfrag = lane & 15;
  const int kfrag = (lane >> 4) * 8;

  for (int k0 = 0; k0 < K; k0 += 32) {
    __syncthreads();
#pragma unroll
    for (int j = 0; j < 2; ++j) {
      const unsigned short* ga = A + (size_t)(brow + srow + j * 16) * K + k0 + scol;
      gload_lds16(ga, As + (w * 1024 + j * 512));
      const unsigned short* gb = B + (size_t)(bcol + srow + j * 16) * K + k0 + scol;
      gload_lds16(gb, Bs + (w * 1024 + j * 512));
    }
    asm volatile("s_waitcnt vmcnt(0)" ::: "memory");
    __syncthreads();
    s16x8 a[4], b[4];
#pragma unroll
    for (int m = 0; m < 4; ++m)
      a[m] = *(const s16x8*)(As + (wr + m * 16 + rfrag) * 32 + kfrag);
#pragma unroll
    for (int n = 0; n < 4; ++n)
      b[n] = *(const s16x8*)(Bs + (wc + n * 16 + rfrag) * 32 + kfrag);
#pragma unroll
    for (int m = 0; m < 4; ++m)
#pragma unroll
      for (int n = 0; n < 4; ++n)
        acc[m][n] = __builtin_amdgcn_mfma_f32_16x16x32_bf16(a[m], b[n], acc[m][n], 0, 0, 0);
  }

  const int crow = brow + wr + ((lane >> 4) * 4);
  const int ccol = bcol + wc + (lane & 15);
  float bv[4];
  if (RELU_BIAS) {
#pragma unroll
    for (int n = 0; n < 4; ++n) bv[n] = bias[ccol + n * 16];
  }
#pragma unroll
  for (int m = 0; m < 4; ++m)
#pragma unroll
    for (int n = 0; n < 4; ++n)
#pragma unroll
      for (int r = 0; r < 4; ++r) {
        float vv = acc[m][n][r];
        if (RELU_BIAS) vv = fmaxf(vv + bv[n], 0.f);
        C[(size_t)(crow + m * 16 + r) * N + ccol + n * 16] = f2bf(vv);
      }
}

// Flash attention. 1D grid 1024 blocks (32 q-tiles x 32 bh), 256 threads
// (4 waves, 16 q-rows each). XCD-aware id remap: xcd = L&7 owns bh in
// [4*xcd, 4*xcd+4) so its KV working set (4MB) fits one L2.
// LDS map (u16): Ks [0,8192) row-major [64][128] col-XOR-swizzled;
//                Vs [8192,16384) subtiled [k/4][d/16][4][16];
//                Pt [16384,20480) per-wave [16 ktile][4][16] subtiled.
// smaskF: f32[2048] additive mask (-1e30 masked / 0).
// Loop: counted vmcnt(4) + raw barriers; K(t+1) staged after QK reads,
// V(t+1) staged after PV reads. 8 gload_lds in flight max per wave.
__global__ __launch_bounds__(256, 4) void attn_fused(
    const unsigned short* __restrict__ Qp, const unsigned short* __restrict__ Kp,
    const unsigned short* __restrict__ Vp, const int* __restrict__ mask,
    unsigned short* __restrict__ Att) {
  constexpr int DD = 1024, NK = 2048;
  __shared__ __align__(16) unsigned short lds[20480];
  __shared__ __align__(16) float smaskF[2048];
  unsigned short* Ks = lds;
  unsigned short* Vs = lds + 8192;
  unsigned short* Pt = lds + 16384;

  const int tid = threadIdx.x, lane = tid & 63, w = tid >> 6;
  const int L = blockIdx.x;
  const int bh = (L & 7) * 4 + (L >> 8);   // 4 heads per XCD
  const int qt = (L >> 3) & 31;
  const int b = bh >> 3, h = bh & 7;
  const int q0 = qt * 64;
  const unsigned short* Qbase = Qp + ((size_t)b * 2048 + q0) * DD + h * 128;
  const unsigned short* Kbase = Kp + (size_t)b * 2048 * DD + h * 128;
  const unsigned short* Vbase = Vp + (size_t)b * 2048 * DD + h * 128;

  // ---- stage Q tile [64][128] (linear, in Ks area) then hoist frags ----
#pragma unroll
  for (int j = 0; j < 4; ++j) {
    int row = w * 16 + j * 4 + (lane >> 4);
    const unsigned short* g = Qbase + (size_t)row * DD + (lane & 15) * 8;
    gload_lds16(g, lds + w * 2048 + j * 512);
  }
  asm volatile("s_waitcnt vmcnt(0)" ::: "memory");
  __syncthreads();
  s16x8 qf[4];
#pragma unroll
  for (int ks = 0; ks < 4; ++ks)
    qf[ks] = *(const s16x8*)(lds + (w * 16 + (lane & 15)) * 128 +
                             ks * 32 + (lane >> 4) * 8);

  // ---- preload full mask row -> smaskF ----
  {
    const int4* mp = (const int4*)(mask + b * NK);
    int4 m0 = mp[tid];
    int4 m1 = mp[tid + 256];
    f32x4 w0, w1;
    w0[0] = m0.x ? -1e30f : 0.f; w0[1] = m0.y ? -1e30f : 0.f;
    w0[2] = m0.z ? -1e30f : 0.f; w0[3] = m0.w ? -1e30f : 0.f;
    w1[0] = m1.x ? -1e30f : 0.f; w1[1] = m1.y ? -1e30f : 0.f;
    w1[2] = m1.z ? -1e30f : 0.f; w1[3] = m1.w ? -1e30f : 0.f;
    *(f32x4*)(smaskF + 4 * tid) = w0;
    *(f32x4*)(smaskF + 4 * (tid + 256)) = w1;
  }
  __syncthreads();  // qf reads + smask writes done; Ks free for K(0)

  auto stageK = [&](int t) {
    const int kk0 = t * 64;
#pragma unroll
    for (int j = 0; j < 4; ++j) {
      int row = w * 16 + j * 4 + (lane >> 4);
      int cb = (lane & 15) * 16;             // byte chunk within 256B row
      int cbs = cb ^ ((row & 7) << 4);       // involution on bits 4..6
      const unsigned short* g = Kbase + (size_t)(kk0 + row) * DD + (cbs >> 1);
      gload_lds16(g, Ks + w * 2048 + j * 512);
    }
  };
  auto stageV = [&](int t) {
    const int kk0 = t * 64;
#pragma unroll
    for (int it = 0; it < 4; ++it) {
      int s = w * 256 + it * 64 + lane;
      int kk = ((s >> 6) << 2) | ((s >> 1) & 3);
      int dd = (((s >> 3) & 7) << 4) | ((s & 1) << 3);
      const unsigned short* g = Vbase + (size_t)(kk0 + kk) * DD + dd;
      gload_lds16(g, Vs + (size_t)(w * 256 + it * 64) * 8);
    }
  };

  stageK(0);
  stageV(0);

  const unsigned vb0 = lds_off(Vs);
  const unsigned pt0b = lds_off(Pt + w * 1024);

  f32x4 o[8] = {};
  float mrow[4], lrow[4];
#pragma unroll
  for (int r = 0; r < 4; ++r) { mrow[r] = -1e30f; lrow[r] = 0.f; }

  for (int kt = 0; kt < NK / 64; ++kt) {
    const int k0 = kt * 64;
    // ---- K(t) arrival: own K done after vmcnt(4); barrier -> all waves ----
    asm volatile("s_waitcnt vmcnt(4)" ::: "memory");
    asm volatile("s_waitcnt lgkmcnt(0)" ::: "memory");
    __builtin_amdgcn_s_barrier();
    __builtin_amdgcn_sched_barrier(0);

    // ---- S = (Q K^T)/32 + mask ----
    f32x4 s[4];
    __builtin_amdgcn_s_setprio(1);
#pragma unroll
    for (int n = 0; n < 4; ++n) {
      f32x4 acc = {};
#pragma unroll
      for (int ks = 0; ks < 4; ++ks) {
        int row = n * 16 + (lane & 15);
        int cb = (ks * 32 + (lane >> 4) * 8) * 2;
        int cbs = cb ^ ((row & 7) << 4);
        s16x8 bf = *(const s16x8*)((const char*)(Ks + row * 128) + cbs);
        acc = __builtin_amdgcn_mfma_f32_16x16x32_bf16(qf[ks], bf, acc, 0, 0, 0);
      }
      float ma = smaskF[k0 + n * 16 + (lane & 15)];
#pragma unroll
      for (int r = 0; r < 4; ++r) acc[r] = fmaf(acc[r], 0.03125f, ma);
      s[n] = acc;
    }
    __builtin_amdgcn_s_setprio(0);

    // ---- Ks reads done -> stage K(t+1) (overlaps softmax+PV) ----
    asm volatile("s_waitcnt lgkmcnt(0)" ::: "memory");
    __builtin_amdgcn_s_barrier();
    __builtin_amdgcn_sched_barrier(0);
    stageK(kt + 1);  // t=32 reads junk inside ws, never consumed

    // ---- online softmax ----
    float tm[4];
#pragma unroll
    for (int r = 0; r < 4; ++r)
      tm[r] = fmaxf(fmaxf(s[0][r], s[1][r]), fmaxf(s[2][r], s[3][r]));
#pragma unroll
    for (int d = 1; d < 16; d <<= 1)
#pragma unroll
      for (int r = 0; r < 4; ++r)
        tm[r] = fmaxf(tm[r], __shfl_xor(tm[r], d, 64));
    // T13 defer-max
    float mx = fmaxf(fmaxf(tm[0] - mrow[0], tm[1] - mrow[1]),
                     fmaxf(tm[2] - mrow[2], tm[3] - mrow[3]));
    const bool up = !__all(mx <= 8.f);
    float al[4], rs[4];
#pragma unroll
    for (int r = 0; r < 4; ++r) {
      float mn = up ? fmaxf(mrow[r], tm[r]) : mrow[r];
      al[r] = __expf(mrow[r] - mn);  // ==1 when !up
      mrow[r] = mn;
      rs[r] = 0.f;
    }
    // P -> Pt subtiled [k/4][4 krow][16 q]; lane writes 4 consecutive q.
    const int ql = (lane >> 4) * 4;
#pragma unroll
    for (int n = 0; n < 4; ++n) {
      float p0 = __expf(s[n][0] - mrow[0]);
      float p1 = __expf(s[n][1] - mrow[1]);
      float p2 = __expf(s[n][2] - mrow[2]);
      float p3 = __expf(s[n][3] - mrow[3]);
      rs[0] += p0; rs[1] += p1; rs[2] += p2; rs[3] += p3;
      unsigned lo, hi;
      asm("v_cvt_pk_bf16_f32 %0, %1, %2" : "=v"(lo) : "v"(p0), "v"(p1));
      asm("v_cvt_pk_bf16_f32 %0, %1, %2" : "=v"(hi) : "v"(p2), "v"(p3));
      int k = n * 16 + (lane & 15);
      u32x2 pk; pk[0] = lo; pk[1] = hi;
      *(u32x2*)(Pt + w * 1024 + (k >> 2) * 64 + (k & 3) * 16 + ql) = pk;
    }
#pragma unroll
    for (int d = 1; d < 16; d <<= 1)
#pragma unroll
      for (int r = 0; r < 4; ++r)
        rs[r] += __shfl_xor(rs[r], d, 64);
#pragma unroll
    for (int r = 0; r < 4; ++r)
      lrow[r] = lrow[r] * al[r] + rs[r];
    if (up) {
#pragma unroll
      for (int n = 0; n < 8; ++n)
#pragma unroll
        for (int r = 0; r < 4; ++r)
          o[n][r] *= al[r];
    }

    // ---- V(t) arrival ----
    asm volatile("s_waitcnt vmcnt(4)" ::: "memory");
    asm volatile("s_waitcnt lgkmcnt(0)" ::: "memory");
    __builtin_amdgcn_s_barrier();
    __builtin_amdgcn_sched_barrier(0);

    // ---- O += P V: pa + V via ds_read_b64_tr_b16 ----
#pragma unroll
    for (int ks2 = 0; ks2 < 2; ++ks2) {
      // pa: A-frag P[q=lane&15][k=(lane>>4)*8+j]; k-subtile stride 128B.
      const unsigned pbase =
          pt0b + (ks2 * 8 + (lane >> 4) * 2) * 128 + (lane & 15) * 8;
      s16x4 plo, phi;
      asm volatile("ds_read_b64_tr_b16 %0, %2\n\t"
                   "ds_read_b64_tr_b16 %1, %2 offset:128"
                   : "=v"(plo), "=v"(phi) : "v"(pbase) : "memory");
      const unsigned base =
          vb0 + ks2 * 8192 + (lane >> 4) * 2048 + (lane & 15) * 8;
      s16x4 vlo[8], vhi[8];
#pragma unroll
      for (int n = 0; n < 8; ++n) {
        asm volatile("ds_read_b64_tr_b16 %0, %2\n\t"
                     "ds_read_b64_tr_b16 %1, %2 offset:1024"
                     : "=v"(vlo[n]), "=v"(vhi[n])
                     : "v"(base + n * 128)
                     : "memory");
      }
      asm volatile("s_waitcnt lgkmcnt(0)" ::: "memory");
      __builtin_amdgcn_sched_barrier(0);
      s16x8 pa;
#pragma unroll
      for (int j = 0; j < 4; ++j) { pa[j] = plo[j]; pa[4 + j] = phi[j]; }
      __builtin_amdgcn_s_setprio(1);
#pragma unroll
      for (int n = 0; n < 8; ++n) {
        s16x8 vv;
#pragma unroll
        for (int j = 0; j < 4; ++j) { vv[j] = vlo[n][j]; vv[4 + j] = vhi[n][j]; }
        o[n] = __builtin_amdgcn_mfma_f32_16x16x32_bf16(pa, vv, o[n], 0, 0, 0);
      }
      __builtin_amdgcn_s_setprio(0);
    }

    // ---- Vs reads done -> stage V(t+1) (overlaps next QK) ----
    asm volatile("s_waitcnt lgkmcnt(0)" ::: "memory");
    __builtin_amdgcn_s_barrier();
    __builtin_amdgcn_sched_barrier(0);
    stageV(kt + 1);
  }

  // drain trailing prefetches before LDS goes away / stores
  asm volatile("s_waitcnt vmcnt(0)" ::: "memory");

  // ---- normalize + write ----
  float inv[4];
#pragma unroll
  for (int r = 0; r < 4; ++r) {
    float den = lrow[r];
    inv[r] = (mrow[r] <= -1e29f || den <= 0.f) ? 0.f : 1.f / den;
  }
#pragma unroll
  for (int n = 0; n < 8; ++n)
#pragma unroll
    for (int r = 0; r < 4; ++r) {
      int q = q0 + w * 16 + (lane >> 4) * 4 + r;
      Att[((size_t)b * 2048 + q) * DD + h * 128 + n * 16 + (lane & 15)] =
          f2bf(o[n][r] * inv[r]);
    }
}

// out = LayerNorm(X + Y) * g + b. One block per 1024-elem row.
template<int OUT_F32>
__global__ __launch_bounds__(256) void add_ln(
    const unsigned short* __restrict__ X, const unsigned short* __restrict__ Y,
    const float* __restrict__ gam, const float* __restrict__ bet,
    void* __restrict__ out) {
  const int row = blockIdx.x;
  const int tid = threadIdx.x;
  const int lane = tid & 63, w = tid >> 6;
  __shared__ float rbuf[8];
  const size_t base = (size_t)row * 1024 + tid * 4;
  s16x4 xa = *(const s16x4*)(X + base);
  s16x4 yb = *(const s16x4*)(Y + base);
  float x[4];
  float s1 = 0.f, s2 = 0.f;
#pragma unroll
  for (int j = 0; j < 4; ++j) {
    x[j] = bf2f((unsigned short)xa[j]) + bf2f((unsigned short)yb[j]);
    s1 += x[j];
    s2 += x[j] * x[j];
  }
#pragma unroll
  for (int d = 1; d < 64; d <<= 1) {
    s1 += __shfl_xor(s1, d, 64);
    s2 += __shfl_xor(s2, d, 64);
  }
  if (lane == 0) { rbuf[w] = s1; rbuf[4 + w] = s2; }
  __syncthreads();
  float t1 = rbuf[0] + rbuf[1] + rbuf[2] + rbuf[3];
  float t2 = rbuf[4] + rbuf[5] + rbuf[6] + rbuf[7];
  float mu = t1 * (1.f / 1024.f);
  float var = t2 * (1.f / 1024.f) - mu * mu;
  float rstd = rsqrtf(fmaxf(var, 0.f) + 1e-5f);
  float4 g4 = *(const float4*)(gam + tid * 4);
  float4 b4 = *(const float4*)(bet + tid * 4);
  float gg[4] = {g4.x, g4.y, g4.z, g4.w};
  float bb[4] = {b4.x, b4.y, b4.z, b4.w};
  if (OUT_F32) {
    float4 o4;
    o4.x = (x[0] - mu) * rstd * gg[0] + bb[0];
    o4.y = (x[1] - mu) * rstd * gg[1] + bb[1];
    o4.z = (x[2] - mu) * rstd * gg[2] + bb[2];
    o4.w = (x[3] - mu) * rstd * gg[3] + bb[3];
    *(float4*)((float*)out + base) = o4;
  } else {
    s16x4 o;
#pragma unroll
    for (int j = 0; j < 4; ++j)
      o[j] = (short)f2bf((x[j] - mu) * rstd * gg[j] + bb[j]);
    *(s16x4*)((unsigned short*)out + base) = o;
  }
}

extern "C" void kernel_launch(void* const* d_in, const int* in_sizes, int n_in,
                              void* d_out, int out_size, void* d_ws, size_t ws_size,
                              hipStream_t stream) {
  const float* q  = (const float*)d_in[0];
  const float* k  = (const float*)d_in[1];
  const float* v  = (const float*)d_in[2];
  const int* msk  = (const int*)d_in[3];
  const float* Wq = (const float*)d_in[4];
  const float* Wk = (const float*)d_in[5];
  const float* Wv = (const float*)d_in[6];
  const float* Wo = (const float*)d_in[7];
  const float* bo = (const float*)d_in[8];
  const float* g1 = (const float*)d_in[9];
  const float* b1 = (const float*)d_in[10];
  const float* g2 = (const float*)d_in[11];
  const float* b2 = (const float*)d_in[12];
  float* out = (float*)d_out;

  char* ws = (char*)d_ws;
  const size_t S = (size_t)8192 * 1024 * 2;
  unsigned short* qb  = (unsigned short*)(ws + 0 * S);
  unsigned short* kb  = (unsigned short*)(ws + 1 * S);
  unsigned short* vb  = (unsigned short*)(ws + 2 * S);
  unsigned short* qpb = (unsigned short*)(ws + 3 * S);
  unsigned short* kpb = (unsigned short*)(ws + 4 * S);
  unsigned short* vpb = (unsigned short*)(ws + 5 * S);
  unsigned short* attb = qb;  // reuse: q bf16 dead after proj
  unsigned short* h1b  = kb;
  unsigned short* h2b  = vb;
  unsigned short* Wqb = (unsigned short*)(ws + 6 * S);
  unsigned short* Wkb = Wqb + (size_t)1024 * 1024;
  unsigned short* Wvb = Wkb + (size_t)1024 * 1024;
  unsigned short* Wob = Wvb + (size_t)1024 * 1024;

  const int n4big = 8192 * 1024 / 4;
  const int n4w   = 1024 * 1024 / 4;
  cvt_f32_bf16<<<8192, 256, 0, stream>>>(q, qb, n4big);
  cvt_f32_bf16<<<8192, 256, 0, stream>>>(k, kb, n4big);
  cvt_f32_bf16<<<8192, 256, 0, stream>>>(v, vb, n4big);
  cvt_f32_bf16<<<1024, 256, 0, stream>>>(Wq, Wqb, n4w);
  cvt_f32_bf16<<<1024, 256, 0, stream>>>(Wk, Wkb, n4w);
  cvt_f32_bf16<<<1024, 256, 0, stream>>>(Wv, Wvb, n4w);
  cvt_f32_bf16<<<1024, 256, 0, stream>>>(Wo, Wob, n4w);

  dim3 gg(64, 8);
  gemm_bt<0><<<gg, 256, 0, stream>>>(qb, Wqb, qpb, nullptr, 8192, 1024, 1024);
  gemm_bt<0><<<gg, 256, 0, stream>>>(kb, Wkb, kpb, nullptr, 8192, 1024, 1024);
  gemm_bt<0><<<gg, 256, 0, stream>>>(vb, Wvb, vpb, nullptr, 8192, 1024, 1024);

  attn_fused<<<1024, 256, 0, stream>>>(qpb, kpb, vpb, msk, attb);

  add_ln<0><<<8192, 256, 0, stream>>>(qpb, attb, g1, b1, (void*)h1b);
  gemm_bt<1><<<gg, 256, 0, stream>>>(h1b, Wob, h2b, bo, 8192, 1024, 1024);
  add_ln<1><<<8192, 256, 0, stream>>>(h1b, h2b, g2, b2, (void*)out);
}

// Round 5
// 316.691 us; speedup vs baseline: 1.1478x; 1.1478x over previous
//
#include <hip/hip_runtime.h>

// MultiHeadAttn fused block, MI355X/gfx950.
// Round 5: swapped-QK^T attention (S^T = mfma(K,Q)) -> in-lane softmax
// (15-op trees + 2 shfl instead of 32), scalar m/l per lane, P packed via
// v_cvt_pk_bf16_f32 into per-wave swizzled PL[q][k], PV A-frag = 2x
// ds_read_b128. Round-3 loop skeleton (2 syncthreads/tile), V tr-read path.

typedef __attribute__((ext_vector_type(4))) float f32x4;
typedef __attribute__((ext_vector_type(8))) short s16x8;
typedef __attribute__((ext_vector_type(4))) short s16x4;
typedef __attribute__((ext_vector_type(2))) unsigned int u32x2;

__device__ __forceinline__ unsigned short f2bf(float f) {
  union { float f; unsigned u; } x; x.f = f;
  unsigned r = x.u + 0x7fffu + ((x.u >> 16) & 1u);
  return (unsigned short)(r >> 16);
}
__device__ __forceinline__ float bf2f(unsigned short h) {
  union { unsigned u; float f; } x; x.u = ((unsigned)h) << 16;
  return x.f;
}

__device__ __forceinline__ void gload_lds16(const void* g, void* l) {
  __builtin_amdgcn_global_load_lds(
      (const __attribute__((address_space(1))) unsigned int*)g,
      (__attribute__((address_space(3))) unsigned int*)l, 16, 0, 0);
}

__device__ __forceinline__ unsigned lds_off(const void* p) {
  return (unsigned)(size_t)(const __attribute__((address_space(3))) void*)p;
}

__global__ __launch_bounds__(256) void cvt_f32_bf16(
    const float* __restrict__ src, unsigned short* __restrict__ dst, int n4) {
  int i = blockIdx.x * blockDim.x + threadIdx.x;
  if (i >= n4) return;
  float4 f = reinterpret_cast<const float4*>(src)[i];
  s16x4 o;
  o[0] = (short)f2bf(f.x); o[1] = (short)f2bf(f.y);
  o[2] = (short)f2bf(f.z); o[3] = (short)f2bf(f.w);
  reinterpret_cast<s16x4*>(dst)[i] = o;
}

// C[M,N] = A[M,K] @ B[N,K]^T, all bf16 (C bf16 out), optional bias+relu epilogue.
// 128x128 tile, BK=32, 4 waves (2x2), 4x4 16x16x32 frags per wave.
template<int RELU_BIAS>
__global__ __launch_bounds__(256) void gemm_bt(
    const unsigned short* __restrict__ A, const unsigned short* __restrict__ B,
    unsigned short* __restrict__ C, const float* __restrict__ bias,
    int M, int N, int K) {
  __shared__ __align__(16) unsigned short As[128 * 32];
  __shared__ __align__(16) unsigned short Bs[128 * 32];
  const int tid = threadIdx.x;
  const int lane = tid & 63;
  const int w = tid >> 6;
  const int brow = blockIdx.x * 128;
  const int bcol = blockIdx.y * 128;
  const int wr = (w >> 1) * 64;
  const int wc = (w & 1) * 64;

  f32x4 acc[4][4] = {};

  const int srow = w * 32 + (lane >> 2);  // + j*16
  const int scol = (lane & 3) * 8;
  const int rfrag = lane & 15;
  const int kfrag = (lane >> 4) * 8;

  for (int k0 = 0; k0 < K; k0 += 32) {
    __syncthreads();
#pragma unroll
    for (int j = 0; j < 2; ++j) {
      const unsigned short* ga = A + (size_t)(brow + srow + j * 16) * K + k0 + scol;
      gload_lds16(ga, As + (w * 1024 + j * 512));
      const unsigned short* gb = B + (size_t)(bcol + srow + j * 16) * K + k0 + scol;
      gload_lds16(gb, Bs + (w * 1024 + j * 512));
    }
    asm volatile("s_waitcnt vmcnt(0)" ::: "memory");
    __syncthreads();
    s16x8 a[4], b[4];
#pragma unroll
    for (int m = 0; m < 4; ++m)
      a[m] = *(const s16x8*)(As + (wr + m * 16 + rfrag) * 32 + kfrag);
#pragma unroll
    for (int n = 0; n < 4; ++n)
      b[n] = *(const s16x8*)(Bs + (wc + n * 16 + rfrag) * 32 + kfrag);
#pragma unroll
    for (int m = 0; m < 4; ++m)
#pragma unroll
      for (int n = 0; n < 4; ++n)
        acc[m][n] = __builtin_amdgcn_mfma_f32_16x16x32_bf16(a[m], b[n], acc[m][n], 0, 0, 0);
  }

  const int crow = brow + wr + ((lane >> 4) * 4);
  const int ccol = bcol + wc + (lane & 15);
  float bv[4];
  if (RELU_BIAS) {
#pragma unroll
    for (int n = 0; n < 4; ++n) bv[n] = bias[ccol + n * 16];
  }
#pragma unroll
  for (int m = 0; m < 4; ++m)
#pragma unroll
    for (int n = 0; n < 4; ++n)
#pragma unroll
      for (int r = 0; r < 4; ++r) {
        float vv = acc[m][n][r];
        if (RELU_BIAS) vv = fmaxf(vv + bv[n], 0.f);
        C[(size_t)(crow + m * 16 + r) * N + ccol + n * 16] = f2bf(vv);
      }
}

// Flash attention. 1D grid 1024 blocks (32 q-tiles x 32 bh), 256 threads
// (4 waves, 16 q-rows each). XCD-aware id remap: xcd = L&7 owns bh in
// [4*xcd, 4*xcd+4) so its KV working set (4MB) fits one L2.
// LDS map (u16): Ks [0,8192) [64][128] col-XOR-swizzled;
//                Vs [8192,16384) subtiled [k/4][d/16][4][16];
//                PL [16384,20480) per-wave [16 q][64 k] bf16, XOR-swizzled.
// smaskF: f32[2048] additive mask (-1e30 masked / 0).
// Swapped QK^T: S^T = mfma(Kfrag, Qfrag) -> lane owns q=lane&15,
// k = n*16 + (lane>>4)*4 + r. Softmax in-lane; m/l scalar per lane.
__global__ __launch_bounds__(256, 4) void attn_fused(
    const unsigned short* __restrict__ Qp, const unsigned short* __restrict__ Kp,
    const unsigned short* __restrict__ Vp, const int* __restrict__ mask,
    unsigned short* __restrict__ Att) {
  constexpr int DD = 1024, NK = 2048;
  __shared__ __align__(16) unsigned short lds[20480];
  __shared__ __align__(16) float smaskF[2048];
  unsigned short* Ks = lds;
  unsigned short* Vs = lds + 8192;

  const int tid = threadIdx.x, lane = tid & 63, w = tid >> 6;
  const int quad = lane >> 4, lq = lane & 15;
  const int L = blockIdx.x;
  const int bh = (L & 7) * 4 + (L >> 8);   // 4 heads per XCD
  const int qt = (L >> 3) & 31;
  const int b = bh >> 3, h = bh & 7;
  const int q0 = qt * 64;
  const unsigned short* Qbase = Qp + ((size_t)b * 2048 + q0) * DD + h * 128;
  const unsigned short* Kbase = Kp + (size_t)b * 2048 * DD + h * 128;
  const unsigned short* Vbase = Vp + (size_t)b * 2048 * DD + h * 128;
  char* PLw = (char*)(lds + 16384 + w * 1024);

  // ---- stage Q tile [64][128] (linear, in Ks area) then hoist frags ----
#pragma unroll
  for (int j = 0; j < 4; ++j) {
    int row = w * 16 + j * 4 + quad;
    const unsigned short* g = Qbase + (size_t)row * DD + lq * 8;
    gload_lds16(g, lds + w * 2048 + j * 512);
  }
  asm volatile("s_waitcnt vmcnt(0)" ::: "memory");
  __syncthreads();
  s16x8 qf[4];  // B-operand frags: col = q = lq, k-dim slice = quad*8
#pragma unroll
  for (int ks = 0; ks < 4; ++ks)
    qf[ks] = *(const s16x8*)(lds + (w * 16 + lq) * 128 + ks * 32 + quad * 8);

  // ---- preload full additive mask row -> smaskF ----
  {
    const int4* mp = (const int4*)(mask + b * NK);
    int4 m0 = mp[tid];
    int4 m1 = mp[tid + 256];
    f32x4 w0, w1;
    w0[0] = m0.x ? -1e30f : 0.f; w0[1] = m0.y ? -1e30f : 0.f;
    w0[2] = m0.z ? -1e30f : 0.f; w0[3] = m0.w ? -1e30f : 0.f;
    w1[0] = m1.x ? -1e30f : 0.f; w1[1] = m1.y ? -1e30f : 0.f;
    w1[2] = m1.z ? -1e30f : 0.f; w1[3] = m1.w ? -1e30f : 0.f;
    *(f32x4*)(smaskF + 4 * tid) = w0;
    *(f32x4*)(smaskF + 4 * (tid + 256)) = w1;
  }

  const unsigned vb0 = lds_off(Vs);
  const int plq = lq & 7;  // swizzle bits for PL row

  f32x4 o[8] = {};
  float mrow = -1e30f, lrow = 0.f;

  for (int kt = 0; kt < NK / 64; ++kt) {
    const int k0 = kt * 64;
    __syncthreads();  // prior iteration's LDS reads done before overwrite
    // stage K [64][128] with XOR-swizzled SOURCE (linear LDS dest)
#pragma unroll
    for (int j = 0; j < 4; ++j) {
      int row = w * 16 + j * 4 + quad;
      int cb = lq * 16;                      // byte chunk within 256B row
      int cbs = cb ^ ((row & 7) << 4);       // involution on bits 4..6
      const unsigned short* g = Kbase + (size_t)(k0 + row) * DD + (cbs >> 1);
      gload_lds16(g, Ks + w * 2048 + j * 512);
    }
    // stage V into subtile layout [k/4][d/16][4][16] via pre-swizzled source
#pragma unroll
    for (int it = 0; it < 4; ++it) {
      int s = w * 256 + it * 64 + lane;
      int kk = ((s >> 6) << 2) | ((s >> 1) & 3);
      int dd = (((s >> 3) & 7) << 4) | ((s & 1) << 3);
      const unsigned short* g = Vbase + (size_t)(k0 + kk) * DD + dd;
      gload_lds16(g, Vs + (size_t)(w * 256 + it * 64) * 8);
    }
    asm volatile("s_waitcnt vmcnt(0)" ::: "memory");
    __syncthreads();

    // ---- S^T = (K Q^T)/32 + mask: lane owns q=lq, k = n*16 + quad*4 + r ----
    f32x4 s[4];
    __builtin_amdgcn_s_setprio(1);
#pragma unroll
    for (int n = 0; n < 4; ++n) {
      f32x4 acc = {};
#pragma unroll
      for (int ks = 0; ks < 4; ++ks) {
        int row = n * 16 + lq;
        int cb = (ks * 32 + quad * 8) * 2;
        int cbs = cb ^ ((row & 7) << 4);
        s16x8 kf = *(const s16x8*)((const char*)(Ks + row * 128) + cbs);
        acc = __builtin_amdgcn_mfma_f32_16x16x32_bf16(kf, qf[ks], acc, 0, 0, 0);
      }
      f32x4 ma = *(const f32x4*)(smaskF + k0 + n * 16 + quad * 4);
#pragma unroll
      for (int r = 0; r < 4; ++r) acc[r] = fmaf(acc[r], 0.03125f, ma[r]);
      s[n] = acc;
    }
    __builtin_amdgcn_s_setprio(0);

    // ---- online softmax, in-lane ----
    float tm = fmaxf(fmaxf(fmaxf(s[0][0], s[0][1]), fmaxf(s[0][2], s[0][3])),
                     fmaxf(fmaxf(s[1][0], s[1][1]), fmaxf(s[1][2], s[1][3])));
    tm = fmaxf(tm,
               fmaxf(fmaxf(fmaxf(s[2][0], s[2][1]), fmaxf(s[2][2], s[2][3])),
                     fmaxf(fmaxf(s[3][0], s[3][1]), fmaxf(s[3][2], s[3][3]))));
    tm = fmaxf(tm, __shfl_xor(tm, 16, 64));
    tm = fmaxf(tm, __shfl_xor(tm, 32, 64));
    // T13 defer-max
    const bool up = !__all(tm - mrow <= 8.f);
    float al = 1.f;
    if (up) {
      float mn = fmaxf(mrow, tm);
      al = __expf(mrow - mn);
      mrow = mn;
    }
    // P = exp(S - m), pack to bf16, write PL[q][k] (XOR-swizzled)
    float rs = 0.f;
#pragma unroll
    for (int n = 0; n < 4; ++n) {
      float p0 = __expf(s[n][0] - mrow);
      float p1 = __expf(s[n][1] - mrow);
      float p2 = __expf(s[n][2] - mrow);
      float p3 = __expf(s[n][3] - mrow);
      rs += (p0 + p1) + (p2 + p3);
      unsigned lo, hi;
      asm("v_cvt_pk_bf16_f32 %0, %1, %2" : "=v"(lo) : "v"(p0), "v"(p1));
      asm("v_cvt_pk_bf16_f32 %0, %1, %2" : "=v"(hi) : "v"(p2), "v"(p3));
      u32x2 pk; pk[0] = lo; pk[1] = hi;
      int byteoff = (lq * 128 + n * 32 + quad * 8) ^ (plq << 4);
      *(u32x2*)(PLw + byteoff) = pk;
    }
    rs += __shfl_xor(rs, 16, 64);
    rs += __shfl_xor(rs, 32, 64);
    lrow = lrow * al + rs;
    if (up) {
      float alo[4];
#pragma unroll
      for (int r = 0; r < 4; ++r)
        alo[r] = __shfl(al, (lane & 48) | (quad * 4 + r), 64);
#pragma unroll
      for (int n = 0; n < 8; ++n)
#pragma unroll
        for (int r = 0; r < 4; ++r)
          o[n][r] *= alo[r];
    }

    // ---- O += P V: pa from PL (b128 swizzled), V via ds_read_b64_tr_b16 ----
#pragma unroll
    for (int ks2 = 0; ks2 < 2; ++ks2) {
      s16x8 pa = *(const s16x8*)(
          PLw + ((lq * 128 + ks2 * 64 + quad * 16) ^ (plq << 4)));
      const unsigned base = vb0 + ks2 * 8192 + quad * 2048 + lq * 8;
      s16x4 vlo[8], vhi[8];
#pragma unroll
      for (int n = 0; n < 8; ++n) {
        asm volatile("ds_read_b64_tr_b16 %0, %2\n\t"
                     "ds_read_b64_tr_b16 %1, %2 offset:1024"
                     : "=v"(vlo[n]), "=v"(vhi[n])
                     : "v"(base + n * 128)
                     : "memory");
      }
      asm volatile("s_waitcnt lgkmcnt(0)" ::: "memory");
      __builtin_amdgcn_sched_barrier(0);
      __builtin_amdgcn_s_setprio(1);
#pragma unroll
      for (int n = 0; n < 8; ++n) {
        s16x8 vv;
#pragma unroll
        for (int j = 0; j < 4; ++j) { vv[j] = vlo[n][j]; vv[4 + j] = vhi[n][j]; }
        o[n] = __builtin_amdgcn_mfma_f32_16x16x32_bf16(pa, vv, o[n], 0, 0, 0);
      }
      __builtin_amdgcn_s_setprio(0);
    }
  }

  // ---- normalize + write (broadcast inv from q=lq holder to o rows) ----
  float inv = (mrow <= -1e29f || lrow <= 0.f) ? 0.f : 1.f / lrow;
  float invo[4];
#pragma unroll
  for (int r = 0; r < 4; ++r)
    invo[r] = __shfl(inv, (lane & 48) | (quad * 4 + r), 64);
#pragma unroll
  for (int n = 0; n < 8; ++n)
#pragma unroll
    for (int r = 0; r < 4; ++r) {
      int q = q0 + w * 16 + quad * 4 + r;
      Att[((size_t)b * 2048 + q) * DD + h * 128 + n * 16 + lq] =
          f2bf(o[n][r] * invo[r]);
    }
}

// out = LayerNorm(X + Y) * g + b. One block per 1024-elem row.
template<int OUT_F32>
__global__ __launch_bounds__(256) void add_ln(
    const unsigned short* __restrict__ X, const unsigned short* __restrict__ Y,
    const float* __restrict__ gam, const float* __restrict__ bet,
    void* __restrict__ out) {
  const int row = blockIdx.x;
  const int tid = threadIdx.x;
  const int lane = tid & 63, w = tid >> 6;
  __shared__ float rbuf[8];
  const size_t base = (size_t)row * 1024 + tid * 4;
  s16x4 xa = *(const s16x4*)(X + base);
  s16x4 yb = *(const s16x4*)(Y + base);
  float x[4];
  float s1 = 0.f, s2 = 0.f;
#pragma unroll
  for (int j = 0; j < 4; ++j) {
    x[j] = bf2f((unsigned short)xa[j]) + bf2f((unsigned short)yb[j]);
    s1 += x[j];
    s2 += x[j] * x[j];
  }
#pragma unroll
  for (int d = 1; d < 64; d <<= 1) {
    s1 += __shfl_xor(s1, d, 64);
    s2 += __shfl_xor(s2, d, 64);
  }
  if (lane == 0) { rbuf[w] = s1; rbuf[4 + w] = s2; }
  __syncthreads();
  float t1 = rbuf[0] + rbuf[1] + rbuf[2] + rbuf[3];
  float t2 = rbuf[4] + rbuf[5] + rbuf[6] + rbuf[7];
  float mu = t1 * (1.f / 1024.f);
  float var = t2 * (1.f / 1024.f) - mu * mu;
  float rstd = rsqrtf(fmaxf(var, 0.f) + 1e-5f);
  float4 g4 = *(const float4*)(gam + tid * 4);
  float4 b4 = *(const float4*)(bet + tid * 4);
  float gg[4] = {g4.x, g4.y, g4.z, g4.w};
  float bb[4] = {b4.x, b4.y, b4.z, b4.w};
  if (OUT_F32) {
    float4 o4;
    o4.x = (x[0] - mu) * rstd * gg[0] + bb[0];
    o4.y = (x[1] - mu) * rstd * gg[1] + bb[1];
    o4.z = (x[2] - mu) * rstd * gg[2] + bb[2];
    o4.w = (x[3] - mu) * rstd * gg[3] + bb[3];
    *(float4*)((float*)out + base) = o4;
  } else {
    s16x4 o;
#pragma unroll
    for (int j = 0; j < 4; ++j)
      o[j] = (short)f2bf((x[j] - mu) * rstd * gg[j] + bb[j]);
    *(s16x4*)((unsigned short*)out + base) = o;
  }
}

extern "C" void kernel_launch(void* const* d_in, const int* in_sizes, int n_in,
                              void* d_out, int out_size, void* d_ws, size_t ws_size,
                              hipStream_t stream) {
  const float* q  = (const float*)d_in[0];
  const float* k  = (const float*)d_in[1];
  const float* v  = (const float*)d_in[2];
  const int* msk  = (const int*)d_in[3];
  const float* Wq = (const float*)d_in[4];
  const float* Wk = (const float*)d_in[5];
  const float* Wv = (const float*)d_in[6];
  const float* Wo = (const float*)d_in[7];
  const float* bo = (const float*)d_in[8];
  const float* g1 = (const float*)d_in[9];
  const float* b1 = (const float*)d_in[10];
  const float* g2 = (const float*)d_in[11];
  const float* b2 = (const float*)d_in[12];
  float* out = (float*)d_out;

  char* ws = (char*)d_ws;
  const size_t S = (size_t)8192 * 1024 * 2;
  unsigned short* qb  = (unsigned short*)(ws + 0 * S);
  unsigned short* kb  = (unsigned short*)(ws + 1 * S);
  unsigned short* vb  = (unsigned short*)(ws + 2 * S);
  unsigned short* qpb = (unsigned short*)(ws + 3 * S);
  unsigned short* kpb = (unsigned short*)(ws + 4 * S);
  unsigned short* vpb = (unsigned short*)(ws + 5 * S);
  unsigned short* attb = qb;  // reuse: q bf16 dead after proj
  unsigned short* h1b  = kb;
  unsigned short* h2b  = vb;
  unsigned short* Wqb = (unsigned short*)(ws + 6 * S);
  unsigned short* Wkb = Wqb + (size_t)1024 * 1024;
  unsigned short* Wvb = Wkb + (size_t)1024 * 1024;
  unsigned short* Wob = Wvb + (size_t)1024 * 1024;

  const int n4big = 8192 * 1024 / 4;
  const int n4w   = 1024 * 1024 / 4;
  cvt_f32_bf16<<<8192, 256, 0, stream>>>(q, qb, n4big);
  cvt_f32_bf16<<<8192, 256, 0, stream>>>(k, kb, n4big);
  cvt_f32_bf16<<<8192, 256, 0, stream>>>(v, vb, n4big);
  cvt_f32_bf16<<<1024, 256, 0, stream>>>(Wq, Wqb, n4w);
  cvt_f32_bf16<<<1024, 256, 0, stream>>>(Wk, Wkb, n4w);
  cvt_f32_bf16<<<1024, 256, 0, stream>>>(Wv, Wvb, n4w);
  cvt_f32_bf16<<<1024, 256, 0, stream>>>(Wo, Wob, n4w);

  dim3 gg(64, 8);
  gemm_bt<0><<<gg, 256, 0, stream>>>(qb, Wqb, qpb, nullptr, 8192, 1024, 1024);
  gemm_bt<0><<<gg, 256, 0, stream>>>(kb, Wkb, kpb, nullptr, 8192, 1024, 1024);
  gemm_bt<0><<<gg, 256, 0, stream>>>(vb, Wvb, vpb, nullptr, 8192, 1024, 1024);

  attn_fused<<<1024, 256, 0, stream>>>(qpb, kpb, vpb, msk, attb);

  add_ln<0><<<8192, 256, 0, stream>>>(qpb, attb, g1, b1, (void*)h1b);
  gemm_bt<1><<<gg, 256, 0, stream>>>(h1b, Wob, h2b, bo, 8192, 1024, 1024);
  add_ln<1><<<8192, 256, 0, stream>>>(h1b, h2b, g2, b2, (void*)out);
}

// Round 8
// 308.232 us; speedup vs baseline: 1.1793x; 1.0274x over previous
//
#include <hip/hip_runtime.h>

// MultiHeadAttn fused block, MI355X/gfx950.
// Round 8: attn reverted to round-5 exact (known-pass, 164us). Converts
// merged 7 launches -> 2 (cvt_multi). Round-7 g2 attn kept as a compiled
// but NEVER-LAUNCHED kernel (module-load diagnostic).

typedef __attribute__((ext_vector_type(4))) float f32x4;
typedef __attribute__((ext_vector_type(8))) short s16x8;
typedef __attribute__((ext_vector_type(4))) short s16x4;
typedef __attribute__((ext_vector_type(2))) unsigned int u32x2;

__device__ __forceinline__ unsigned short f2bf(float f) {
  union { float f; unsigned u; } x; x.f = f;
  unsigned r = x.u + 0x7fffu + ((x.u >> 16) & 1u);
  return (unsigned short)(r >> 16);
}
__device__ __forceinline__ float bf2f(unsigned short h) {
  union { unsigned u; float f; } x; x.u = ((unsigned)h) << 16;
  return x.f;
}

__device__ __forceinline__ void gload_lds16(const void* g, void* l) {
  __builtin_amdgcn_global_load_lds(
      (const __attribute__((address_space(1))) unsigned int*)g,
      (__attribute__((address_space(3))) unsigned int*)l, 16, 0, 0);
}

__device__ __forceinline__ unsigned lds_off(const void* p) {
  return (unsigned)(size_t)(const __attribute__((address_space(3))) void*)p;
}

// 4-way batched f32 -> bf16 convert; blockIdx.y selects tensor.
__global__ __launch_bounds__(256) void cvt_multi(
    const float* __restrict__ s0, const float* __restrict__ s1,
    const float* __restrict__ s2, const float* __restrict__ s3,
    unsigned short* __restrict__ d0, unsigned short* __restrict__ d1,
    unsigned short* __restrict__ d2, unsigned short* __restrict__ d3,
    int n4) {
  const int by = blockIdx.y;
  const float* s = by == 0 ? s0 : by == 1 ? s1 : by == 2 ? s2 : s3;
  unsigned short* d = by == 0 ? d0 : by == 1 ? d1 : by == 2 ? d2 : d3;
  int i = blockIdx.x * blockDim.x + threadIdx.x;
  if (i >= n4) return;
  float4 f = reinterpret_cast<const float4*>(s)[i];
  s16x4 o;
  o[0] = (short)f2bf(f.x); o[1] = (short)f2bf(f.y);
  o[2] = (short)f2bf(f.z); o[3] = (short)f2bf(f.w);
  reinterpret_cast<s16x4*>(d)[i] = o;
}

// C[M,N] = A[M,K] @ B[N,K]^T, all bf16 (C bf16 out), optional bias+relu epilogue.
// 128x128 tile, BK=32, 4 waves (2x2), 4x4 16x16x32 frags per wave.
template<int RELU_BIAS>
__global__ __launch_bounds__(256) void gemm_bt(
    const unsigned short* __restrict__ A, const unsigned short* __restrict__ B,
    unsigned short* __restrict__ C, const float* __restrict__ bias,
    int M, int N, int K) {
  __shared__ __align__(16) unsigned short As[128 * 32];
  __shared__ __align__(16) unsigned short Bs[128 * 32];
  const int tid = threadIdx.x;
  const int lane = tid & 63;
  const int w = tid >> 6;
  const int brow = blockIdx.x * 128;
  const int bcol = blockIdx.y * 128;
  const int wr = (w >> 1) * 64;
  const int wc = (w & 1) * 64;

  f32x4 acc[4][4] = {};

  const int srow = w * 32 + (lane >> 2);  // + j*16
  const int scol = (lane & 3) * 8;
  const int rfrag = lane & 15;
  const int kfrag = (lane >> 4) * 8;

  for (int k0 = 0; k0 < K; k0 += 32) {
    __syncthreads();
#pragma unroll
    for (int j = 0; j < 2; ++j) {
      const unsigned short* ga = A + (size_t)(brow + srow + j * 16) * K + k0 + scol;
      gload_lds16(ga, As + (w * 1024 + j * 512));
      const unsigned short* gb = B + (size_t)(bcol + srow + j * 16) * K + k0 + scol;
      gload_lds16(gb, Bs + (w * 1024 + j * 512));
    }
    asm volatile("s_waitcnt vmcnt(0)" ::: "memory");
    __syncthreads();
    s16x8 a[4], b[4];
#pragma unroll
    for (int m = 0; m < 4; ++m)
      a[m] = *(const s16x8*)(As + (wr + m * 16 + rfrag) * 32 + kfrag);
#pragma unroll
    for (int n = 0; n < 4; ++n)
      b[n] = *(const s16x8*)(Bs + (wc + n * 16 + rfrag) * 32 + kfrag);
#pragma unroll
    for (int m = 0; m < 4; ++m)
#pragma unroll
      for (int n = 0; n < 4; ++n)
        acc[m][n] = __builtin_amdgcn_mfma_f32_16x16x32_bf16(a[m], b[n], acc[m][n], 0, 0, 0);
  }

  const int crow = brow + wr + ((lane >> 4) * 4);
  const int ccol = bcol + wc + (lane & 15);
  float bv[4];
  if (RELU_BIAS) {
#pragma unroll
    for (int n = 0; n < 4; ++n) bv[n] = bias[ccol + n * 16];
  }
#pragma unroll
  for (int m = 0; m < 4; ++m)
#pragma unroll
    for (int n = 0; n < 4; ++n)
#pragma unroll
      for (int r = 0; r < 4; ++r) {
        float vv = acc[m][n][r];
        if (RELU_BIAS) vv = fmaxf(vv + bv[n], 0.f);
        C[(size_t)(crow + m * 16 + r) * N + ccol + n * 16] = f2bf(vv);
      }
}

// ===== Round-5 attention (known pass): 1024 blocks, 4 waves, 16 q/wave =====
__global__ __launch_bounds__(256, 4) void attn_fused(
    const unsigned short* __restrict__ Qp, const unsigned short* __restrict__ Kp,
    const unsigned short* __restrict__ Vp, const int* __restrict__ mask,
    unsigned short* __restrict__ Att) {
  constexpr int DD = 1024, NK = 2048;
  __shared__ __align__(16) unsigned short lds[20480];
  __shared__ __align__(16) float smaskF[2048];
  unsigned short* Ks = lds;
  unsigned short* Vs = lds + 8192;

  const int tid = threadIdx.x, lane = tid & 63, w = tid >> 6;
  const int quad = lane >> 4, lq = lane & 15;
  const int L = blockIdx.x;
  const int bh = (L & 7) * 4 + (L >> 8);   // 4 heads per XCD
  const int qt = (L >> 3) & 31;
  const int b = bh >> 3, h = bh & 7;
  const int q0 = qt * 64;
  const unsigned short* Qbase = Qp + ((size_t)b * 2048 + q0) * DD + h * 128;
  const unsigned short* Kbase = Kp + (size_t)b * 2048 * DD + h * 128;
  const unsigned short* Vbase = Vp + (size_t)b * 2048 * DD + h * 128;
  char* PLw = (char*)(lds + 16384 + w * 1024);

  // ---- stage Q tile [64][128] (linear, in Ks area) then hoist frags ----
#pragma unroll
  for (int j = 0; j < 4; ++j) {
    int row = w * 16 + j * 4 + quad;
    const unsigned short* g = Qbase + (size_t)row * DD + lq * 8;
    gload_lds16(g, lds + w * 2048 + j * 512);
  }
  asm volatile("s_waitcnt vmcnt(0)" ::: "memory");
  __syncthreads();
  s16x8 qf[4];  // B-operand frags: col = q = lq, k-dim slice = quad*8
#pragma unroll
  for (int ks = 0; ks < 4; ++ks)
    qf[ks] = *(const s16x8*)(lds + (w * 16 + lq) * 128 + ks * 32 + quad * 8);

  // ---- preload full additive mask row -> smaskF ----
  {
    const int4* mp = (const int4*)(mask + b * NK);
    int4 m0 = mp[tid];
    int4 m1 = mp[tid + 256];
    f32x4 w0, w1;
    w0[0] = m0.x ? -1e30f : 0.f; w0[1] = m0.y ? -1e30f : 0.f;
    w0[2] = m0.z ? -1e30f : 0.f; w0[3] = m0.w ? -1e30f : 0.f;
    w1[0] = m1.x ? -1e30f : 0.f; w1[1] = m1.y ? -1e30f : 0.f;
    w1[2] = m1.z ? -1e30f : 0.f; w1[3] = m1.w ? -1e30f : 0.f;
    *(f32x4*)(smaskF + 4 * tid) = w0;
    *(f32x4*)(smaskF + 4 * (tid + 256)) = w1;
  }

  const unsigned vb0 = lds_off(Vs);
  const int plq = lq & 7;  // swizzle bits for PL row

  f32x4 o[8] = {};
  float mrow = -1e30f, lrow = 0.f;

  for (int kt = 0; kt < NK / 64; ++kt) {
    const int k0 = kt * 64;
    __syncthreads();  // prior iteration's LDS reads done before overwrite
    // stage K [64][128] with XOR-swizzled SOURCE (linear LDS dest)
#pragma unroll
    for (int j = 0; j < 4; ++j) {
      int row = w * 16 + j * 4 + quad;
      int cb = lq * 16;                      // byte chunk within 256B row
      int cbs = cb ^ ((row & 7) << 4);       // involution on bits 4..6
      const unsigned short* g = Kbase + (size_t)(k0 + row) * DD + (cbs >> 1);
      gload_lds16(g, Ks + w * 2048 + j * 512);
    }
    // stage V into subtile layout [k/4][d/16][4][16] via pre-swizzled source
#pragma unroll
    for (int it = 0; it < 4; ++it) {
      int s = w * 256 + it * 64 + lane;
      int kk = ((s >> 6) << 2) | ((s >> 1) & 3);
      int dd = (((s >> 3) & 7) << 4) | ((s & 1) << 3);
      const unsigned short* g = Vbase + (size_t)(k0 + kk) * DD + dd;
      gload_lds16(g, Vs + (size_t)(w * 256 + it * 64) * 8);
    }
    asm volatile("s_waitcnt vmcnt(0)" ::: "memory");
    __syncthreads();

    // ---- S^T = (K Q^T)/32 + mask: lane owns q=lq, k = n*16 + quad*4 + r ----
    f32x4 s[4];
    __builtin_amdgcn_s_setprio(1);
#pragma unroll
    for (int n = 0; n < 4; ++n) {
      f32x4 acc = {};
#pragma unroll
      for (int ks = 0; ks < 4; ++ks) {
        int row = n * 16 + lq;
        int cb = (ks * 32 + quad * 8) * 2;
        int cbs = cb ^ ((row & 7) << 4);
        s16x8 kf = *(const s16x8*)((const char*)(Ks + row * 128) + cbs);
        acc = __builtin_amdgcn_mfma_f32_16x16x32_bf16(kf, qf[ks], acc, 0, 0, 0);
      }
      f32x4 ma = *(const f32x4*)(smaskF + k0 + n * 16 + quad * 4);
#pragma unroll
      for (int r = 0; r < 4; ++r) acc[r] = fmaf(acc[r], 0.03125f, ma[r]);
      s[n] = acc;
    }
    __builtin_amdgcn_s_setprio(0);

    // ---- online softmax, in-lane ----
    float tm = fmaxf(fmaxf(fmaxf(s[0][0], s[0][1]), fmaxf(s[0][2], s[0][3])),
                     fmaxf(fmaxf(s[1][0], s[1][1]), fmaxf(s[1][2], s[1][3])));
    tm = fmaxf(tm,
               fmaxf(fmaxf(fmaxf(s[2][0], s[2][1]), fmaxf(s[2][2], s[2][3])),
                     fmaxf(fmaxf(s[3][0], s[3][1]), fmaxf(s[3][2], s[3][3]))));
    tm = fmaxf(tm, __shfl_xor(tm, 16, 64));
    tm = fmaxf(tm, __shfl_xor(tm, 32, 64));
    // T13 defer-max
    const bool up = !__all(tm - mrow <= 8.f);
    float al = 1.f;
    if (up) {
      float mn = fmaxf(mrow, tm);
      al = __expf(mrow - mn);
      mrow = mn;
    }
    // P = exp(S - m), pack to bf16, write PL[q][k] (XOR-swizzled)
    float rs = 0.f;
#pragma unroll
    for (int n = 0; n < 4; ++n) {
      float p0 = __expf(s[n][0] - mrow);
      float p1 = __expf(s[n][1] - mrow);
      float p2 = __expf(s[n][2] - mrow);
      float p3 = __expf(s[n][3] - mrow);
      rs += (p0 + p1) + (p2 + p3);
      unsigned lo, hi;
      asm("v_cvt_pk_bf16_f32 %0, %1, %2" : "=v"(lo) : "v"(p0), "v"(p1));
      asm("v_cvt_pk_bf16_f32 %0, %1, %2" : "=v"(hi) : "v"(p2), "v"(p3));
      u32x2 pk; pk[0] = lo; pk[1] = hi;
      int byteoff = (lq * 128 + n * 32 + quad * 8) ^ (plq << 4);
      *(u32x2*)(PLw + byteoff) = pk;
    }
    rs += __shfl_xor(rs, 16, 64);
    rs += __shfl_xor(rs, 32, 64);
    lrow = lrow * al + rs;
    if (up) {
      float alo[4];
#pragma unroll
      for (int r = 0; r < 4; ++r)
        alo[r] = __shfl(al, (lane & 48) | (quad * 4 + r), 64);
#pragma unroll
      for (int n = 0; n < 8; ++n)
#pragma unroll
        for (int r = 0; r < 4; ++r)
          o[n][r] *= alo[r];
    }

    // ---- O += P V: pa from PL (b128 swizzled), V via ds_read_b64_tr_b16 ----
#pragma unroll
    for (int ks2 = 0; ks2 < 2; ++ks2) {
      s16x8 pa = *(const s16x8*)(
          PLw + ((lq * 128 + ks2 * 64 + quad * 16) ^ (plq << 4)));
      const unsigned base = vb0 + ks2 * 8192 + quad * 2048 + lq * 8;
      s16x4 vlo[8], vhi[8];
#pragma unroll
      for (int n = 0; n < 8; ++n) {
        asm volatile("ds_read_b64_tr_b16 %0, %2\n\t"
                     "ds_read_b64_tr_b16 %1, %2 offset:1024"
                     : "=v"(vlo[n]), "=v"(vhi[n])
                     : "v"(base + n * 128)
                     : "memory");
      }
      asm volatile("s_waitcnt lgkmcnt(0)" ::: "memory");
      __builtin_amdgcn_sched_barrier(0);
      __builtin_amdgcn_s_setprio(1);
#pragma unroll
      for (int n = 0; n < 8; ++n) {
        s16x8 vv;
#pragma unroll
        for (int j = 0; j < 4; ++j) { vv[j] = vlo[n][j]; vv[4 + j] = vhi[n][j]; }
        o[n] = __builtin_amdgcn_mfma_f32_16x16x32_bf16(pa, vv, o[n], 0, 0, 0);
      }
      __builtin_amdgcn_s_setprio(0);
    }
  }

  // ---- normalize + write (broadcast inv from q=lq holder to o rows) ----
  float inv = (mrow <= -1e29f || lrow <= 0.f) ? 0.f : 1.f / lrow;
  float invo[4];
#pragma unroll
  for (int r = 0; r < 4; ++r)
    invo[r] = __shfl(inv, (lane & 48) | (quad * 4 + r), 64);
#pragma unroll
  for (int n = 0; n < 8; ++n)
#pragma unroll
    for (int r = 0; r < 4; ++r) {
      int q = q0 + w * 16 + quad * 4 + r;
      Att[((size_t)b * 2048 + q) * DD + h * 128 + n * 16 + lq] =
          f2bf(o[n][r] * invo[r]);
    }
}

// ===== DIAGNOSTIC ONLY — round-7 g2 attn, compiled but NEVER launched. =====
// If the module fails to load because of this kernel, this round fails with
// the 6.09 zero-output signature -> confirms compile/load as round-6/7 cause.
__global__ __launch_bounds__(256, 2) void attn_g2probe(
    const unsigned short* __restrict__ Qp, const unsigned short* __restrict__ Kp,
    const unsigned short* __restrict__ Vp, const int* __restrict__ mask,
    unsigned short* __restrict__ Att) {
  constexpr int DD = 1024, NK = 2048;
  __shared__ __align__(16) unsigned short lds[24576];
  __shared__ __align__(16) float smaskF[2048];
  unsigned short* Ks = lds;
  unsigned short* Vs = lds + 8192;

  const int tid = threadIdx.x, lane = tid & 63, w = tid >> 6;
  const int quad = lane >> 4, lq = lane & 15;
  const int L = blockIdx.x;
  const int bh = (L & 7) * 4 + (L >> 7);
  const int qt = (L >> 3) & 15;
  const int b = bh >> 3, h = bh & 7;
  const int q0 = qt * 128;
  const unsigned short* Qbase = Qp + ((size_t)b * 2048 + q0) * DD + h * 128;
  const unsigned short* Kbase = Kp + (size_t)b * 2048 * DD + h * 128;
  const unsigned short* Vbase = Vp + (size_t)b * 2048 * DD + h * 128;
  char* PLw = (char*)(lds + 16384 + w * 2048);

#pragma unroll
  for (int j = 0; j < 8; ++j) {
    int row = w * 32 + j * 4 + quad;
    const unsigned short* g = Qbase + (size_t)row * DD + lq * 8;
    gload_lds16(g, lds + w * 4096 + j * 512);
  }
  asm volatile("s_waitcnt vmcnt(0)" ::: "memory");
  __syncthreads();
  s16x8 qf[2][4];
#pragma unroll
  for (int g = 0; g < 2; ++g)
#pragma unroll
    for (int ks = 0; ks < 4; ++ks)
      qf[g][ks] = *(const s16x8*)(lds + (w * 32 + g * 16 + lq) * 128 +
                                  ks * 32 + quad * 8);

  {
    const int4* mp = (const int4*)(mask + b * NK);
    int4 m0 = mp[tid];
    int4 m1 = mp[tid + 256];
    f32x4 w0, w1;
    w0[0] = m0.x ? -1e30f : 0.f; w0[1] = m0.y ? -1e30f : 0.f;
    w0[2] = m0.z ? -1e30f : 0.f; w0[3] = m0.w ? -1e30f : 0.f;
    w1[0] = m1.x ? -1e30f : 0.f; w1[1] = m1.y ? -1e30f : 0.f;
    w1[2] = m1.z ? -1e30f : 0.f; w1[3] = m1.w ? -1e30f : 0.f;
    *(f32x4*)(smaskF + 4 * tid) = w0;
    *(f32x4*)(smaskF + 4 * (tid + 256)) = w1;
  }

  const unsigned vb0 = lds_off(Vs);
  const unsigned swz = (unsigned)((lq & 7) << 4);

  f32x4 o[2][8] = {};
  float mrow[2] = {-1e30f, -1e30f}, lrow[2] = {0.f, 0.f};

  for (int kt = 0; kt < NK / 64; ++kt) {
    const int k0 = kt * 64;
    __syncthreads();
#pragma unroll
    for (int j = 0; j < 4; ++j) {
      int row = w * 16 + j * 4 + quad;
      int cb = lq * 16;
      int cbs = cb ^ ((row & 7) << 4);
      const unsigned short* g = Kbase + (size_t)(k0 + row) * DD + (cbs >> 1);
      gload_lds16(g, Ks + w * 2048 + j * 512);
    }
#pragma unroll
    for (int it = 0; it < 4; ++it) {
      int s = w * 256 + it * 64 + lane;
      int kk = ((s >> 6) << 2) | ((s >> 1) & 3);
      int dd = (((s >> 3) & 7) << 4) | ((s & 1) << 3);
      const unsigned short* g = Vbase + (size_t)(k0 + kk) * DD + dd;
      gload_lds16(g, Vs + (size_t)(w * 256 + it * 64) * 8);
    }
    asm volatile("s_waitcnt vmcnt(0)" ::: "memory");
    __syncthreads();

    f32x4 s[2][4];
#pragma unroll
    for (int n = 0; n < 4; ++n) {
      f32x4 a0 = {}, a1 = {};
#pragma unroll
      for (int ks = 0; ks < 4; ++ks) {
        int row = n * 16 + lq;
        int cb = (ks * 32 + quad * 8) * 2;
        int cbs = cb ^ ((row & 7) << 4);
        s16x8 kf = *(const s16x8*)((const char*)(Ks + row * 128) + cbs);
        a0 = __builtin_amdgcn_mfma_f32_16x16x32_bf16(kf, qf[0][ks], a0, 0, 0, 0);
        a1 = __builtin_amdgcn_mfma_f32_16x16x32_bf16(kf, qf[1][ks], a1, 0, 0, 0);
      }
      f32x4 ma = *(const f32x4*)(smaskF + k0 + n * 16 + quad * 4);
#pragma unroll
      for (int r = 0; r < 4; ++r) {
        s[0][n][r] = fmaf(a0[r], 0.03125f, ma[r]);
        s[1][n][r] = fmaf(a1[r], 0.03125f, ma[r]);
      }
    }

    float tm[2];
#pragma unroll
    for (int g = 0; g < 2; ++g) {
      float t = fmaxf(fmaxf(fmaxf(s[g][0][0], s[g][0][1]), fmaxf(s[g][0][2], s[g][0][3])),
                      fmaxf(fmaxf(s[g][1][0], s[g][1][1]), fmaxf(s[g][1][2], s[g][1][3])));
      t = fmaxf(t,
                fmaxf(fmaxf(fmaxf(s[g][2][0], s[g][2][1]), fmaxf(s[g][2][2], s[g][2][3])),
                      fmaxf(fmaxf(s[g][3][0], s[g][3][1]), fmaxf(s[g][3][2], s[g][3][3]))));
      t = fmaxf(t, __shfl_xor(t, 16, 64));
      t = fmaxf(t, __shfl_xor(t, 32, 64));
      tm[g] = t;
    }
    const bool up = !__all(fmaxf(tm[0] - mrow[0], tm[1] - mrow[1]) <= 8.f);
    float al[2] = {1.f, 1.f};
    if (up) {
#pragma unroll
      for (int g = 0; g < 2; ++g) {
        float mn = fmaxf(mrow[g], tm[g]);
        al[g] = __expf(mrow[g] - mn);
        mrow[g] = mn;
      }
    }
    float rs[2] = {0.f, 0.f};
#pragma unroll
    for (int g = 0; g < 2; ++g) {
#pragma unroll
      for (int n = 0; n < 4; ++n) {
        float p0 = __expf(s[g][n][0] - mrow[g]);
        float p1 = __expf(s[g][n][1] - mrow[g]);
        float p2 = __expf(s[g][n][2] - mrow[g]);
        float p3 = __expf(s[g][n][3] - mrow[g]);
        rs[g] += (p0 + p1) + (p2 + p3);
        unsigned lo, hi;
        asm("v_cvt_pk_bf16_f32 %0, %1, %2" : "=v"(lo) : "v"(p0), "v"(p1));
        asm("v_cvt_pk_bf16_f32 %0, %1, %2" : "=v"(hi) : "v"(p2), "v"(p3));
        u32x2 pk; pk[0] = lo; pk[1] = hi;
        int byteoff = (((g * 16 + lq) * 128) + n * 32 + quad * 8) ^ swz;
        *(u32x2*)(PLw + byteoff) = pk;
      }
      rs[g] += __shfl_xor(rs[g], 16, 64);
      rs[g] += __shfl_xor(rs[g], 32, 64);
      lrow[g] = lrow[g] * al[g] + rs[g];
    }
    if (up) {
#pragma unroll
      for (int g = 0; g < 2; ++g) {
        float alo[4];
#pragma unroll
        for (int r = 0; r < 4; ++r)
          alo[r] = __shfl(al[g], (lane & 48) | (quad * 4 + r), 64);
#pragma unroll
        for (int n = 0; n < 8; ++n)
#pragma unroll
          for (int r = 0; r < 4; ++r)
            o[g][n][r] *= alo[r];
      }
    }

#pragma unroll
    for (int ks2 = 0; ks2 < 2; ++ks2) {
      s16x8 pa[2];
#pragma unroll
      for (int g = 0; g < 2; ++g)
        pa[g] = *(const s16x8*)(
            PLw + ((((g * 16 + lq) * 128) + ks2 * 64 + quad * 16) ^ swz));
      const unsigned base = vb0 + ks2 * 8192 + quad * 2048 + lq * 8;
      s16x4 vlo[8], vhi[8];
#pragma unroll
      for (int n = 0; n < 8; ++n) {
        asm volatile("ds_read_b64_tr_b16 %0, %2\n\t"
                     "ds_read_b64_tr_b16 %1, %2 offset:1024"
                     : "=v"(vlo[n]), "=v"(vhi[n])
                     : "v"(base + n * 128)
                     : "memory");
      }
      asm volatile("s_waitcnt lgkmcnt(0)" ::: "memory");
      __builtin_amdgcn_sched_barrier(0);
#pragma unroll
      for (int n = 0; n < 8; ++n) {
        s16x8 vv;
#pragma unroll
        for (int j = 0; j < 4; ++j) { vv[j] = vlo[n][j]; vv[4 + j] = vhi[n][j]; }
        o[0][n] = __builtin_amdgcn_mfma_f32_16x16x32_bf16(pa[0], vv, o[0][n], 0, 0, 0);
        o[1][n] = __builtin_amdgcn_mfma_f32_16x16x32_bf16(pa[1], vv, o[1][n], 0, 0, 0);
      }
    }
  }

#pragma unroll
  for (int g = 0; g < 2; ++g) {
    float inv = (mrow[g] <= -1e29f || lrow[g] <= 0.f) ? 0.f : 1.f / lrow[g];
    float invo[4];
#pragma unroll
    for (int r = 0; r < 4; ++r)
      invo[r] = __shfl(inv, (lane & 48) | (quad * 4 + r), 64);
#pragma unroll
    for (int n = 0; n < 8; ++n)
#pragma unroll
      for (int r = 0; r < 4; ++r) {
        int q = q0 + w * 32 + g * 16 + quad * 4 + r;
        Att[((size_t)b * 2048 + q) * DD + h * 128 + n * 16 + lq] =
            f2bf(o[g][n][r] * invo[r]);
      }
  }
}

// out = LayerNorm(X + Y) * g + b. One block per 1024-elem row.
template<int OUT_F32>
__global__ __launch_bounds__(256) void add_ln(
    const unsigned short* __restrict__ X, const unsigned short* __restrict__ Y,
    const float* __restrict__ gam, const float* __restrict__ bet,
    void* __restrict__ out) {
  const int row = blockIdx.x;
  const int tid = threadIdx.x;
  const int lane = tid & 63, w = tid >> 6;
  __shared__ float rbuf[8];
  const size_t base = (size_t)row * 1024 + tid * 4;
  s16x4 xa = *(const s16x4*)(X + base);
  s16x4 yb = *(const s16x4*)(Y + base);
  float x[4];
  float s1 = 0.f, s2 = 0.f;
#pragma unroll
  for (int j = 0; j < 4; ++j) {
    x[j] = bf2f((unsigned short)xa[j]) + bf2f((unsigned short)yb[j]);
    s1 += x[j];
    s2 += x[j] * x[j];
  }
#pragma unroll
  for (int d = 1; d < 64; d <<= 1) {
    s1 += __shfl_xor(s1, d, 64);
    s2 += __shfl_xor(s2, d, 64);
  }
  if (lane == 0) { rbuf[w] = s1; rbuf[4 + w] = s2; }
  __syncthreads();
  float t1 = rbuf[0] + rbuf[1] + rbuf[2] + rbuf[3];
  float t2 = rbuf[4] + rbuf[5] + rbuf[6] + rbuf[7];
  float mu = t1 * (1.f / 1024.f);
  float var = t2 * (1.f / 1024.f) - mu * mu;
  float rstd = rsqrtf(fmaxf(var, 0.f) + 1e-5f);
  float4 g4 = *(const float4*)(gam + tid * 4);
  float4 b4 = *(const float4*)(bet + tid * 4);
  float gg[4] = {g4.x, g4.y, g4.z, g4.w};
  float bb[4] = {b4.x, b4.y, b4.z, b4.w};
  if (OUT_F32) {
    float4 o4;
    o4.x = (x[0] - mu) * rstd * gg[0] + bb[0];
    o4.y = (x[1] - mu) * rstd * gg[1] + bb[1];
    o4.z = (x[2] - mu) * rstd * gg[2] + bb[2];
    o4.w = (x[3] - mu) * rstd * gg[3] + bb[3];
    *(float4*)((float*)out + base) = o4;
  } else {
    s16x4 o;
#pragma unroll
    for (int j = 0; j < 4; ++j)
      o[j] = (short)f2bf((x[j] - mu) * rstd * gg[j] + bb[j]);
    *(s16x4*)((unsigned short*)out + base) = o;
  }
}

extern "C" void kernel_launch(void* const* d_in, const int* in_sizes, int n_in,
                              void* d_out, int out_size, void* d_ws, size_t ws_size,
                              hipStream_t stream) {
  const float* q  = (const float*)d_in[0];
  const float* k  = (const float*)d_in[1];
  const float* v  = (const float*)d_in[2];
  const int* msk  = (const int*)d_in[3];
  const float* Wq = (const float*)d_in[4];
  const float* Wk = (const float*)d_in[5];
  const float* Wv = (const float*)d_in[6];
  const float* Wo = (const float*)d_in[7];
  const float* bo = (const float*)d_in[8];
  const float* g1 = (const float*)d_in[9];
  const float* b1 = (const float*)d_in[10];
  const float* g2 = (const float*)d_in[11];
  const float* b2 = (const float*)d_in[12];
  float* out = (float*)d_out;

  char* ws = (char*)d_ws;
  const size_t S = (size_t)8192 * 1024 * 2;
  unsigned short* qb  = (unsigned short*)(ws + 0 * S);
  unsigned short* kb  = (unsigned short*)(ws + 1 * S);
  unsigned short* vb  = (unsigned short*)(ws + 2 * S);
  unsigned short* qpb = (unsigned short*)(ws + 3 * S);
  unsigned short* kpb = (unsigned short*)(ws + 4 * S);
  unsigned short* vpb = (unsigned short*)(ws + 5 * S);
  unsigned short* attb = qb;  // reuse: q bf16 dead after proj
  unsigned short* h1b  = kb;
  unsigned short* h2b  = vb;
  unsigned short* Wqb = (unsigned short*)(ws + 6 * S);
  unsigned short* Wkb = Wqb + (size_t)1024 * 1024;
  unsigned short* Wvb = Wkb + (size_t)1024 * 1024;
  unsigned short* Wob = Wvb + (size_t)1024 * 1024;

  const int n4big = 8192 * 1024 / 4;
  const int n4w   = 1024 * 1024 / 4;
  // q/k/v converts in one launch (y selects tensor; 4th slot unused dup).
  cvt_multi<<<dim3(8192, 3), 256, 0, stream>>>(q, k, v, v, qb, kb, vb, vb, n4big);
  // 4 weight converts in one launch.
  cvt_multi<<<dim3(1024, 4), 256, 0, stream>>>(Wq, Wk, Wv, Wo, Wqb, Wkb, Wvb, Wob, n4w);

  dim3 gg(64, 8);
  gemm_bt<0><<<gg, 256, 0, stream>>>(qb, Wqb, qpb, nullptr, 8192, 1024, 1024);
  gemm_bt<0><<<gg, 256, 0, stream>>>(kb, Wkb, kpb, nullptr, 8192, 1024, 1024);
  gemm_bt<0><<<gg, 256, 0, stream>>>(vb, Wvb, vpb, nullptr, 8192, 1024, 1024);

  attn_fused<<<1024, 256, 0, stream>>>(qpb, kpb, vpb, msk, attb);

  add_ln<0><<<8192, 256, 0, stream>>>(qpb, attb, g1, b1, (void*)h1b);
  gemm_bt<1><<<gg, 256, 0, stream>>>(h1b, Wob, h2b, bo, 8192, 1024, 1024);
  add_ln<1><<<8192, 256, 0, stream>>>(h1b, h2b, g2, b2, (void*)out);
}

// Round 9
// 260.196 us; speedup vs baseline: 1.3970x; 1.1846x over previous
//
#include <hip/hip_runtime.h>

// MultiHeadAttn fused block, MI355X/gfx950.
// Round 9: attn rewritten on mfma_f32_32x32x16_bf16 (swapped QK^T).
// 32 q-rows/wave from single fragments (no duplicated-group code path),
// halving K/V LDS traffic per q-row. C layout (m74/m101): col=lane&31,
// row=(reg&3)+8*(reg>>2)+4*(lane>>5). Everything else from round 8.

typedef __attribute__((ext_vector_type(4))) float f32x4;
typedef __attribute__((ext_vector_type(16))) float f32x16;
typedef __attribute__((ext_vector_type(8))) short s16x8;
typedef __attribute__((ext_vector_type(4))) short s16x4;
typedef __attribute__((ext_vector_type(2))) unsigned int u32x2;

__device__ __forceinline__ unsigned short f2bf(float f) {
  union { float f; unsigned u; } x; x.f = f;
  unsigned r = x.u + 0x7fffu + ((x.u >> 16) & 1u);
  return (unsigned short)(r >> 16);
}
__device__ __forceinline__ float bf2f(unsigned short h) {
  union { unsigned u; float f; } x; x.u = ((unsigned)h) << 16;
  return x.f;
}

__device__ __forceinline__ void gload_lds16(const void* g, void* l) {
  __builtin_amdgcn_global_load_lds(
      (const __attribute__((address_space(1))) unsigned int*)g,
      (__attribute__((address_space(3))) unsigned int*)l, 16, 0, 0);
}

__device__ __forceinline__ unsigned lds_off(const void* p) {
  return (unsigned)(size_t)(const __attribute__((address_space(3))) void*)p;
}

// 4-way batched f32 -> bf16 convert; blockIdx.y selects tensor.
__global__ __launch_bounds__(256) void cvt_multi(
    const float* __restrict__ s0, const float* __restrict__ s1,
    const float* __restrict__ s2, const float* __restrict__ s3,
    unsigned short* __restrict__ d0, unsigned short* __restrict__ d1,
    unsigned short* __restrict__ d2, unsigned short* __restrict__ d3,
    int n4) {
  const int by = blockIdx.y;
  const float* s = by == 0 ? s0 : by == 1 ? s1 : by == 2 ? s2 : s3;
  unsigned short* d = by == 0 ? d0 : by == 1 ? d1 : by == 2 ? d2 : d3;
  int i = blockIdx.x * blockDim.x + threadIdx.x;
  if (i >= n4) return;
  float4 f = reinterpret_cast<const float4*>(s)[i];
  s16x4 o;
  o[0] = (short)f2bf(f.x); o[1] = (short)f2bf(f.y);
  o[2] = (short)f2bf(f.z); o[3] = (short)f2bf(f.w);
  reinterpret_cast<s16x4*>(d)[i] = o;
}

// C[M,N] = A[M,K] @ B[N,K]^T, all bf16 (C bf16 out), optional bias+relu epilogue.
// 128x128 tile, BK=32, 4 waves (2x2), 4x4 16x16x32 frags per wave.
template<int RELU_BIAS>
__global__ __launch_bounds__(256) void gemm_bt(
    const unsigned short* __restrict__ A, const unsigned short* __restrict__ B,
    unsigned short* __restrict__ C, const float* __restrict__ bias,
    int M, int N, int K) {
  __shared__ __align__(16) unsigned short As[128 * 32];
  __shared__ __align__(16) unsigned short Bs[128 * 32];
  const int tid = threadIdx.x;
  const int lane = tid & 63;
  const int w = tid >> 6;
  const int brow = blockIdx.x * 128;
  const int bcol = blockIdx.y * 128;
  const int wr = (w >> 1) * 64;
  const int wc = (w & 1) * 64;

  f32x4 acc[4][4] = {};

  const int srow = w * 32 + (lane >> 2);  // + j*16
  const int scol = (lane & 3) * 8;
  const int rfrag = lane & 15;
  const int kfrag = (lane >> 4) * 8;

  for (int k0 = 0; k0 < K; k0 += 32) {
    __syncthreads();
#pragma unroll
    for (int j = 0; j < 2; ++j) {
      const unsigned short* ga = A + (size_t)(brow + srow + j * 16) * K + k0 + scol;
      gload_lds16(ga, As + (w * 1024 + j * 512));
      const unsigned short* gb = B + (size_t)(bcol + srow + j * 16) * K + k0 + scol;
      gload_lds16(gb, Bs + (w * 1024 + j * 512));
    }
    asm volatile("s_waitcnt vmcnt(0)" ::: "memory");
    __syncthreads();
    s16x8 a[4], b[4];
#pragma unroll
    for (int m = 0; m < 4; ++m)
      a[m] = *(const s16x8*)(As + (wr + m * 16 + rfrag) * 32 + kfrag);
#pragma unroll
    for (int n = 0; n < 4; ++n)
      b[n] = *(const s16x8*)(Bs + (wc + n * 16 + rfrag) * 32 + kfrag);
#pragma unroll
    for (int m = 0; m < 4; ++m)
#pragma unroll
      for (int n = 0; n < 4; ++n)
        acc[m][n] = __builtin_amdgcn_mfma_f32_16x16x32_bf16(a[m], b[n], acc[m][n], 0, 0, 0);
  }

  const int crow = brow + wr + ((lane >> 4) * 4);
  const int ccol = bcol + wc + (lane & 15);
  float bv[4];
  if (RELU_BIAS) {
#pragma unroll
    for (int n = 0; n < 4; ++n) bv[n] = bias[ccol + n * 16];
  }
#pragma unroll
  for (int m = 0; m < 4; ++m)
#pragma unroll
    for (int n = 0; n < 4; ++n)
#pragma unroll
      for (int r = 0; r < 4; ++r) {
        float vv = acc[m][n][r];
        if (RELU_BIAS) vv = fmaxf(vv + bv[n], 0.f);
        C[(size_t)(crow + m * 16 + r) * N + ccol + n * 16] = f2bf(vv);
      }
}

// Flash attention on 32x32x16 MFMA. Grid 512 (16 q-tiles x 32 bh), 256 thr
// (4 waves x 32 q-rows). XCD remap: xcd = L&7 owns bh in [4*xcd, 4*xcd+4).
// LDS (u16): Ks [0,8192) [64][128] col-XOR-swizzled rows (256B, swz bits4-6);
//            Vs [8192,16384) subtiled [kt=k/4][dt=d/16][4][16];
//            PL [16384,24576) per-wave [32 q][64 k] bf16, XOR-swizzled.
// smaskF: f32[2048] additive mask. Q [128][128] staged in Ks+Vs pre-loop.
// Swapped QK^T: S^T = mfma32(Kfrag, Qfrag): lane owns q = lane&31;
// k rows = kb*32 + (reg&3) + 8*(reg>>2) + 4*(lane>>5). Softmax in-lane.
__global__ __launch_bounds__(256, 2) void attn_fused(
    const unsigned short* __restrict__ Qp, const unsigned short* __restrict__ Kp,
    const unsigned short* __restrict__ Vp, const int* __restrict__ mask,
    unsigned short* __restrict__ Att) {
  constexpr int DD = 1024, NK = 2048;
  __shared__ __align__(16) unsigned short lds[24576];
  __shared__ __align__(16) float smaskF[2048];
  unsigned short* Ks = lds;
  unsigned short* Vs = lds + 8192;

  const int tid = threadIdx.x, lane = tid & 63, w = tid >> 6;
  const int quad = lane >> 4, lq = lane & 15;
  const int hi = lane >> 5, q5 = lane & 31;
  const int L = blockIdx.x;
  const int bh = (L & 7) * 4 + (L >> 7);   // 4 heads per XCD
  const int qt = (L >> 3) & 15;
  const int b = bh >> 3, h = bh & 7;
  const int q0 = qt * 128;
  const unsigned short* Qbase = Qp + ((size_t)b * 2048 + q0) * DD + h * 128;
  const unsigned short* Kbase = Kp + (size_t)b * 2048 * DD + h * 128;
  const unsigned short* Vbase = Vp + (size_t)b * 2048 * DD + h * 128;
  char* PLw = (char*)(lds + 16384 + w * 2048);

  // ---- stage Q tile [128][128] (linear, Ks+Vs area) then hoist frags ----
#pragma unroll
  for (int j = 0; j < 8; ++j) {
    int row = w * 32 + j * 4 + quad;
    const unsigned short* g = Qbase + (size_t)row * DD + lq * 8;
    gload_lds16(g, lds + w * 4096 + j * 512);
  }
  asm volatile("s_waitcnt vmcnt(0)" ::: "memory");
  __syncthreads();
  // B-frag for mfma32: lane holds Q[q = q5 (+w*32)][d = ds*16 + hi*8 + j]
  s16x8 qf[8];
#pragma unroll
  for (int ds = 0; ds < 8; ++ds)
    qf[ds] = *(const s16x8*)(lds + (w * 32 + q5) * 128 + ds * 16 + hi * 8);

  // ---- preload full additive mask row -> smaskF ----
  {
    const int4* mp = (const int4*)(mask + b * NK);
    int4 m0 = mp[tid];
    int4 m1 = mp[tid + 256];
    f32x4 w0, w1;
    w0[0] = m0.x ? -1e30f : 0.f; w0[1] = m0.y ? -1e30f : 0.f;
    w0[2] = m0.z ? -1e30f : 0.f; w0[3] = m0.w ? -1e30f : 0.f;
    w1[0] = m1.x ? -1e30f : 0.f; w1[1] = m1.y ? -1e30f : 0.f;
    w1[2] = m1.z ? -1e30f : 0.f; w1[3] = m1.w ? -1e30f : 0.f;
    *(f32x4*)(smaskF + 4 * tid) = w0;
    *(f32x4*)(smaskF + 4 * (tid + 256)) = w1;
  }

  const unsigned vb0 = lds_off(Vs);
  const int swzq = (q5 & 7) << 4;

  f32x16 o[4] = {};
  float mrow = -1e30f, lrow = 0.f;

  for (int kt = 0; kt < NK / 64; ++kt) {
    const int k0 = kt * 64;
    __syncthreads();  // prior iteration's LDS reads done before overwrite
    // stage K [64][128] with XOR-swizzled SOURCE (linear LDS dest)
#pragma unroll
    for (int j = 0; j < 4; ++j) {
      int row = w * 16 + j * 4 + quad;
      int cb = lq * 16;                      // byte chunk within 256B row
      int cbs = cb ^ ((row & 7) << 4);       // involution on bits 4..6
      const unsigned short* g = Kbase + (size_t)(k0 + row) * DD + (cbs >> 1);
      gload_lds16(g, Ks + w * 2048 + j * 512);
    }
    // stage V into subtile layout [k/4][d/16][4][16] via pre-swizzled source
#pragma unroll
    for (int it = 0; it < 4; ++it) {
      int s = w * 256 + it * 64 + lane;
      int kk = ((s >> 6) << 2) | ((s >> 1) & 3);
      int dd = (((s >> 3) & 7) << 4) | ((s & 1) << 3);
      const unsigned short* g = Vbase + (size_t)(k0 + kk) * DD + dd;
      gload_lds16(g, Vs + (size_t)(w * 256 + it * 64) * 8);
    }
    asm volatile("s_waitcnt vmcnt(0)" ::: "memory");
    __syncthreads();

    // ---- S^T = (K Q^T)/32 + mask ----
    // A-frag: lane holds K[kb*32 + q5][ds*16 + hi*8 + j] (Ks swizzled read).
    f32x16 acc0 = {}, acc1 = {};
    __builtin_amdgcn_s_setprio(1);
#pragma unroll
    for (int ds = 0; ds < 8; ++ds) {
      int cbs = (ds * 32 + hi * 16) ^ swzq;  // row&7 == q5&7 for both kb
      s16x8 kf0 = *(const s16x8*)((const char*)Ks + q5 * 256 + cbs);
      s16x8 kf1 = *(const s16x8*)((const char*)Ks + (q5 + 32) * 256 + cbs);
      acc0 = __builtin_amdgcn_mfma_f32_32x32x16_bf16(kf0, qf[ds], acc0, 0, 0, 0);
      acc1 = __builtin_amdgcn_mfma_f32_32x32x16_bf16(kf1, qf[ds], acc1, 0, 0, 0);
    }
    __builtin_amdgcn_s_setprio(0);

    // scale + mask; reg -> k = kb*32 + (reg&3) + 8*(reg>>2) + 4*hi
    float sv0[16], sv1[16];
#pragma unroll
    for (int g2 = 0; g2 < 4; ++g2) {
      f32x4 m0 = *(const f32x4*)(smaskF + k0 + g2 * 8 + hi * 4);
      f32x4 m1 = *(const f32x4*)(smaskF + k0 + 32 + g2 * 8 + hi * 4);
#pragma unroll
      for (int j2 = 0; j2 < 4; ++j2) {
        sv0[g2 * 4 + j2] = fmaf(acc0[g2 * 4 + j2], 0.03125f, m0[j2]);
        sv1[g2 * 4 + j2] = fmaf(acc1[g2 * 4 + j2], 0.03125f, m1[j2]);
      }
    }

    // ---- online softmax, in-lane over 32 values + one shfl ----
    float tm = fmaxf(sv0[0], sv1[0]);
#pragma unroll
    for (int r = 1; r < 16; ++r) tm = fmaxf(tm, fmaxf(sv0[r], sv1[r]));
    tm = fmaxf(tm, __shfl_xor(tm, 32, 64));
    // T13 defer-max
    const bool up = !__all(tm - mrow <= 8.f);
    float al = 1.f;
    if (up) {
      float mn = fmaxf(mrow, tm);
      al = __expf(mrow - mn);
      mrow = mn;
    }
    // P = exp(S - m) -> bf16 pack -> PL[q][k] (XOR-swizzled)
    float rs = 0.f;
#pragma unroll
    for (int g2 = 0; g2 < 4; ++g2) {
      {
        float p0 = __expf(sv0[g2 * 4 + 0] - mrow);
        float p1 = __expf(sv0[g2 * 4 + 1] - mrow);
        float p2 = __expf(sv0[g2 * 4 + 2] - mrow);
        float p3 = __expf(sv0[g2 * 4 + 3] - mrow);
        rs += (p0 + p1) + (p2 + p3);
        unsigned lo, hi2;
        asm("v_cvt_pk_bf16_f32 %0, %1, %2" : "=v"(lo) : "v"(p0), "v"(p1));
        asm("v_cvt_pk_bf16_f32 %0, %1, %2" : "=v"(hi2) : "v"(p2), "v"(p3));
        u32x2 pk; pk[0] = lo; pk[1] = hi2;
        *(u32x2*)(PLw + ((q5 * 128 + g2 * 16 + hi * 8) ^ swzq)) = pk;
      }
      {
        float p0 = __expf(sv1[g2 * 4 + 0] - mrow);
        float p1 = __expf(sv1[g2 * 4 + 1] - mrow);
        float p2 = __expf(sv1[g2 * 4 + 2] - mrow);
        float p3 = __expf(sv1[g2 * 4 + 3] - mrow);
        rs += (p0 + p1) + (p2 + p3);
        unsigned lo, hi2;
        asm("v_cvt_pk_bf16_f32 %0, %1, %2" : "=v"(lo) : "v"(p0), "v"(p1));
        asm("v_cvt_pk_bf16_f32 %0, %1, %2" : "=v"(hi2) : "v"(p2), "v"(p3));
        u32x2 pk; pk[0] = lo; pk[1] = hi2;
        *(u32x2*)(PLw + ((q5 * 128 + 64 + g2 * 16 + hi * 8) ^ swzq)) = pk;
      }
    }
    rs += __shfl_xor(rs, 32, 64);
    lrow = lrow * al + rs;
    if (up) {
#pragma unroll
      for (int reg = 0; reg < 16; ++reg) {
        float alo = __shfl(al, (reg & 3) + 8 * (reg >> 2) + 4 * hi, 64);
#pragma unroll
        for (int db = 0; db < 4; ++db) o[db][reg] *= alo;
      }
    }

    // ---- O += P V ----
    // A-frag: PL[q = q5][k = kb2*16 + hi*8 + j] (swizzled b128).
    // B-frag: V[k][d = db*32 + q5] via tr-read; per-16-lane-group subtile
    // base with dt = db*2 + (quad&1), kt = kb2*4 + hi*2 (+1 via offset:1024).
#pragma unroll
    for (int db = 0; db < 4; ++db) {
      s16x8 pa[4];
      s16x4 vlo[4], vhi[4];
#pragma unroll
      for (int kb2 = 0; kb2 < 4; ++kb2) {
        pa[kb2] = *(const s16x8*)(
            PLw + ((q5 * 128 + kb2 * 32 + hi * 16) ^ swzq));
        const unsigned va = vb0 + (kb2 * 4 + hi * 2) * 1024 +
                            (db * 2 + (quad & 1)) * 128 + lq * 8;
        asm volatile("ds_read_b64_tr_b16 %0, %2\n\t"
                     "ds_read_b64_tr_b16 %1, %2 offset:1024"
                     : "=&v"(vlo[kb2]), "=&v"(vhi[kb2])
                     : "v"(va)
                     : "memory");
      }
      asm volatile("s_waitcnt lgkmcnt(0)" ::: "memory");
      __builtin_amdgcn_sched_barrier(0);
      __builtin_amdgcn_s_setprio(1);
#pragma unroll
      for (int kb2 = 0; kb2 < 4; ++kb2) {
        s16x8 vv;
#pragma unroll
        for (int j = 0; j < 4; ++j) { vv[j] = vlo[kb2][j]; vv[4 + j] = vhi[kb2][j]; }
        o[db] = __builtin_amdgcn_mfma_f32_32x32x16_bf16(pa[kb2], vv, o[db], 0, 0, 0);
      }
      __builtin_amdgcn_s_setprio(0);
    }
  }

  // ---- normalize + write ----
  float inv = (mrow <= -1e29f || lrow <= 0.f) ? 0.f : 1.f / lrow;
#pragma unroll
  for (int reg = 0; reg < 16; ++reg) {
    const int rown = (reg & 3) + 8 * (reg >> 2) + 4 * hi;
    float invo = __shfl(inv, rown, 64);
    const int q = q0 + w * 32 + rown;
#pragma unroll
    for (int db = 0; db < 4; ++db) {
      Att[((size_t)b * 2048 + q) * DD + h * 128 + db * 32 + q5] =
          f2bf(o[db][reg] * invo);
    }
  }
}

// out = LayerNorm(X + Y) * g + b. One block per 1024-elem row.
template<int OUT_F32>
__global__ __launch_bounds__(256) void add_ln(
    const unsigned short* __restrict__ X, const unsigned short* __restrict__ Y,
    const float* __restrict__ gam, const float* __restrict__ bet,
    void* __restrict__ out) {
  const int row = blockIdx.x;
  const int tid = threadIdx.x;
  const int lane = tid & 63, w = tid >> 6;
  __shared__ float rbuf[8];
  const size_t base = (size_t)row * 1024 + tid * 4;
  s16x4 xa = *(const s16x4*)(X + base);
  s16x4 yb = *(const s16x4*)(Y + base);
  float x[4];
  float s1 = 0.f, s2 = 0.f;
#pragma unroll
  for (int j = 0; j < 4; ++j) {
    x[j] = bf2f((unsigned short)xa[j]) + bf2f((unsigned short)yb[j]);
    s1 += x[j];
    s2 += x[j] * x[j];
  }
#pragma unroll
  for (int d = 1; d < 64; d <<= 1) {
    s1 += __shfl_xor(s1, d, 64);
    s2 += __shfl_xor(s2, d, 64);
  }
  if (lane == 0) { rbuf[w] = s1; rbuf[4 + w] = s2; }
  __syncthreads();
  float t1 = rbuf[0] + rbuf[1] + rbuf[2] + rbuf[3];
  float t2 = rbuf[4] + rbuf[5] + rbuf[6] + rbuf[7];
  float mu = t1 * (1.f / 1024.f);
  float var = t2 * (1.f / 1024.f) - mu * mu;
  float rstd = rsqrtf(fmaxf(var, 0.f) + 1e-5f);
  float4 g4 = *(const float4*)(gam + tid * 4);
  float4 b4 = *(const float4*)(bet + tid * 4);
  float gg[4] = {g4.x, g4.y, g4.z, g4.w};
  float bb[4] = {b4.x, b4.y, b4.z, b4.w};
  if (OUT_F32) {
    float4 o4;
    o4.x = (x[0] - mu) * rstd * gg[0] + bb[0];
    o4.y = (x[1] - mu) * rstd * gg[1] + bb[1];
    o4.z = (x[2] - mu) * rstd * gg[2] + bb[2];
    o4.w = (x[3] - mu) * rstd * gg[3] + bb[3];
    *(float4*)((float*)out + base) = o4;
  } else {
    s16x4 o;
#pragma unroll
    for (int j = 0; j < 4; ++j)
      o[j] = (short)f2bf((x[j] - mu) * rstd * gg[j] + bb[j]);
    *(s16x4*)((unsigned short*)out + base) = o;
  }
}

extern "C" void kernel_launch(void* const* d_in, const int* in_sizes, int n_in,
                              void* d_out, int out_size, void* d_ws, size_t ws_size,
                              hipStream_t stream) {
  const float* q  = (const float*)d_in[0];
  const float* k  = (const float*)d_in[1];
  const float* v  = (const float*)d_in[2];
  const int* msk  = (const int*)d_in[3];
  const float* Wq = (const float*)d_in[4];
  const float* Wk = (const float*)d_in[5];
  const float* Wv = (const float*)d_in[6];
  const float* Wo = (const float*)d_in[7];
  const float* bo = (const float*)d_in[8];
  const float* g1 = (const float*)d_in[9];
  const float* b1 = (const float*)d_in[10];
  const float* g2 = (const float*)d_in[11];
  const float* b2 = (const float*)d_in[12];
  float* out = (float*)d_out;

  char* ws = (char*)d_ws;
  const size_t S = (size_t)8192 * 1024 * 2;
  unsigned short* qb  = (unsigned short*)(ws + 0 * S);
  unsigned short* kb  = (unsigned short*)(ws + 1 * S);
  unsigned short* vb  = (unsigned short*)(ws + 2 * S);
  unsigned short* qpb = (unsigned short*)(ws + 3 * S);
  unsigned short* kpb = (unsigned short*)(ws + 4 * S);
  unsigned short* vpb = (unsigned short*)(ws + 5 * S);
  unsigned short* attb = qb;  // reuse: q bf16 dead after proj
  unsigned short* h1b  = kb;
  unsigned short* h2b  = vb;
  unsigned short* Wqb = (unsigned short*)(ws + 6 * S);
  unsigned short* Wkb = Wqb + (size_t)1024 * 1024;
  unsigned short* Wvb = Wkb + (size_t)1024 * 1024;
  unsigned short* Wob = Wvb + (size_t)1024 * 1024;

  const int n4big = 8192 * 1024 / 4;
  const int n4w   = 1024 * 1024 / 4;
  cvt_multi<<<dim3(8192, 3), 256, 0, stream>>>(q, k, v, v, qb, kb, vb, vb, n4big);
  cvt_multi<<<dim3(1024, 4), 256, 0, stream>>>(Wq, Wk, Wv, Wo, Wqb, Wkb, Wvb, Wob, n4w);

  dim3 gg(64, 8);
  gemm_bt<0><<<gg, 256, 0, stream>>>(qb, Wqb, qpb, nullptr, 8192, 1024, 1024);
  gemm_bt<0><<<gg, 256, 0, stream>>>(kb, Wkb, kpb, nullptr, 8192, 1024, 1024);
  gemm_bt<0><<<gg, 256, 0, stream>>>(vb, Wvb, vpb, nullptr, 8192, 1024, 1024);

  attn_fused<<<512, 256, 0, stream>>>(qpb, kpb, vpb, msk, attb);

  add_ln<0><<<8192, 256, 0, stream>>>(qpb, attb, g1, b1, (void*)h1b);
  gemm_bt<1><<<gg, 256, 0, stream>>>(h1b, Wob, h2b, bo, 8192, 1024, 1024);
  add_ln<1><<<8192, 256, 0, stream>>>(h1b, h2b, g2, b2, (void*)out);
}

// Round 10
// 240.062 us; speedup vs baseline: 1.5141x; 1.0839x over previous
//
#include <hip/hip_runtime.h>

// MultiHeadAttn fused block, MI355X/gfx950.
// Round 10: (1) attn PV: hoist pa[4] PL reads out of the db loop (were
// re-read 4x -> 4x less PL read traffic); (2) 3 projection GEMMs batched
// into one gridDim.z=3 dispatch. Rest identical to round 9 (pass, 260us).

typedef __attribute__((ext_vector_type(4))) float f32x4;
typedef __attribute__((ext_vector_type(16))) float f32x16;
typedef __attribute__((ext_vector_type(8))) short s16x8;
typedef __attribute__((ext_vector_type(4))) short s16x4;
typedef __attribute__((ext_vector_type(2))) unsigned int u32x2;

__device__ __forceinline__ unsigned short f2bf(float f) {
  union { float f; unsigned u; } x; x.f = f;
  unsigned r = x.u + 0x7fffu + ((x.u >> 16) & 1u);
  return (unsigned short)(r >> 16);
}
__device__ __forceinline__ float bf2f(unsigned short h) {
  union { unsigned u; float f; } x; x.u = ((unsigned)h) << 16;
  return x.f;
}

__device__ __forceinline__ void gload_lds16(const void* g, void* l) {
  __builtin_amdgcn_global_load_lds(
      (const __attribute__((address_space(1))) unsigned int*)g,
      (__attribute__((address_space(3))) unsigned int*)l, 16, 0, 0);
}

__device__ __forceinline__ unsigned lds_off(const void* p) {
  return (unsigned)(size_t)(const __attribute__((address_space(3))) void*)p;
}

// 4-way batched f32 -> bf16 convert; blockIdx.y selects tensor.
__global__ __launch_bounds__(256) void cvt_multi(
    const float* __restrict__ s0, const float* __restrict__ s1,
    const float* __restrict__ s2, const float* __restrict__ s3,
    unsigned short* __restrict__ d0, unsigned short* __restrict__ d1,
    unsigned short* __restrict__ d2, unsigned short* __restrict__ d3,
    int n4) {
  const int by = blockIdx.y;
  const float* s = by == 0 ? s0 : by == 1 ? s1 : by == 2 ? s2 : s3;
  unsigned short* d = by == 0 ? d0 : by == 1 ? d1 : by == 2 ? d2 : d3;
  int i = blockIdx.x * blockDim.x + threadIdx.x;
  if (i >= n4) return;
  float4 f = reinterpret_cast<const float4*>(s)[i];
  s16x4 o;
  o[0] = (short)f2bf(f.x); o[1] = (short)f2bf(f.y);
  o[2] = (short)f2bf(f.z); o[3] = (short)f2bf(f.w);
  reinterpret_cast<s16x4*>(d)[i] = o;
}

// C[M,N] = A[M,K] @ B[N,K]^T, all bf16 (C bf16 out), optional bias+relu.
// 128x128 tile, BK=32, 4 waves (2x2), 4x4 16x16x32 frags per wave.
template<int RELU_BIAS>
__global__ __launch_bounds__(256) void gemm_bt(
    const unsigned short* __restrict__ A, const unsigned short* __restrict__ B,
    unsigned short* __restrict__ C, const float* __restrict__ bias,
    int M, int N, int K) {
  __shared__ __align__(16) unsigned short As[128 * 32];
  __shared__ __align__(16) unsigned short Bs[128 * 32];
  const int tid = threadIdx.x;
  const int lane = tid & 63;
  const int w = tid >> 6;
  const int brow = blockIdx.x * 128;
  const int bcol = blockIdx.y * 128;
  const int wr = (w >> 1) * 64;
  const int wc = (w & 1) * 64;

  f32x4 acc[4][4] = {};

  const int srow = w * 32 + (lane >> 2);  // + j*16
  const int scol = (lane & 3) * 8;
  const int rfrag = lane & 15;
  const int kfrag = (lane >> 4) * 8;

  for (int k0 = 0; k0 < K; k0 += 32) {
    __syncthreads();
#pragma unroll
    for (int j = 0; j < 2; ++j) {
      const unsigned short* ga = A + (size_t)(brow + srow + j * 16) * K + k0 + scol;
      gload_lds16(ga, As + (w * 1024 + j * 512));
      const unsigned short* gb = B + (size_t)(bcol + srow + j * 16) * K + k0 + scol;
      gload_lds16(gb, Bs + (w * 1024 + j * 512));
    }
    asm volatile("s_waitcnt vmcnt(0)" ::: "memory");
    __syncthreads();
    s16x8 a[4], b[4];
#pragma unroll
    for (int m = 0; m < 4; ++m)
      a[m] = *(const s16x8*)(As + (wr + m * 16 + rfrag) * 32 + kfrag);
#pragma unroll
    for (int n = 0; n < 4; ++n)
      b[n] = *(const s16x8*)(Bs + (wc + n * 16 + rfrag) * 32 + kfrag);
#pragma unroll
    for (int m = 0; m < 4; ++m)
#pragma unroll
      for (int n = 0; n < 4; ++n)
        acc[m][n] = __builtin_amdgcn_mfma_f32_16x16x32_bf16(a[m], b[n], acc[m][n], 0, 0, 0);
  }

  const int crow = brow + wr + ((lane >> 4) * 4);
  const int ccol = bcol + wc + (lane & 15);
  float bv[4];
  if (RELU_BIAS) {
#pragma unroll
    for (int n = 0; n < 4; ++n) bv[n] = bias[ccol + n * 16];
  }
#pragma unroll
  for (int m = 0; m < 4; ++m)
#pragma unroll
    for (int n = 0; n < 4; ++n)
#pragma unroll
      for (int r = 0; r < 4; ++r) {
        float vv = acc[m][n][r];
        if (RELU_BIAS) vv = fmaxf(vv + bv[n], 0.f);
        C[(size_t)(crow + m * 16 + r) * N + ccol + n * 16] = f2bf(vv);
      }
}

// 3 projection GEMMs in one dispatch; blockIdx.z selects (A,B,C) triple.
__global__ __launch_bounds__(256) void gemm_proj3(
    const unsigned short* __restrict__ A0, const unsigned short* __restrict__ A1,
    const unsigned short* __restrict__ A2, const unsigned short* __restrict__ B0,
    const unsigned short* __restrict__ B1, const unsigned short* __restrict__ B2,
    unsigned short* __restrict__ C0, unsigned short* __restrict__ C1,
    unsigned short* __restrict__ C2, int M, int N, int K) {
  const int z = blockIdx.z;
  const unsigned short* __restrict__ A = z == 0 ? A0 : z == 1 ? A1 : A2;
  const unsigned short* __restrict__ B = z == 0 ? B0 : z == 1 ? B1 : B2;
  unsigned short* __restrict__ C = z == 0 ? C0 : z == 1 ? C1 : C2;

  __shared__ __align__(16) unsigned short As[128 * 32];
  __shared__ __align__(16) unsigned short Bs[128 * 32];
  const int tid = threadIdx.x;
  const int lane = tid & 63;
  const int w = tid >> 6;
  const int brow = blockIdx.x * 128;
  const int bcol = blockIdx.y * 128;
  const int wr = (w >> 1) * 64;
  const int wc = (w & 1) * 64;

  f32x4 acc[4][4] = {};

  const int srow = w * 32 + (lane >> 2);
  const int scol = (lane & 3) * 8;
  const int rfrag = lane & 15;
  const int kfrag = (lane >> 4) * 8;

  for (int k0 = 0; k0 < K; k0 += 32) {
    __syncthreads();
#pragma unroll
    for (int j = 0; j < 2; ++j) {
      const unsigned short* ga = A + (size_t)(brow + srow + j * 16) * K + k0 + scol;
      gload_lds16(ga, As + (w * 1024 + j * 512));
      const unsigned short* gb = B + (size_t)(bcol + srow + j * 16) * K + k0 + scol;
      gload_lds16(gb, Bs + (w * 1024 + j * 512));
    }
    asm volatile("s_waitcnt vmcnt(0)" ::: "memory");
    __syncthreads();
    s16x8 a[4], b[4];
#pragma unroll
    for (int m = 0; m < 4; ++m)
      a[m] = *(const s16x8*)(As + (wr + m * 16 + rfrag) * 32 + kfrag);
#pragma unroll
    for (int n = 0; n < 4; ++n)
      b[n] = *(const s16x8*)(Bs + (wc + n * 16 + rfrag) * 32 + kfrag);
#pragma unroll
    for (int m = 0; m < 4; ++m)
#pragma unroll
      for (int n = 0; n < 4; ++n)
        acc[m][n] = __builtin_amdgcn_mfma_f32_16x16x32_bf16(a[m], b[n], acc[m][n], 0, 0, 0);
  }

  const int crow = brow + wr + ((lane >> 4) * 4);
  const int ccol = bcol + wc + (lane & 15);
#pragma unroll
  for (int m = 0; m < 4; ++m)
#pragma unroll
    for (int n = 0; n < 4; ++n)
#pragma unroll
      for (int r = 0; r < 4; ++r)
        C[(size_t)(crow + m * 16 + r) * N + ccol + n * 16] = f2bf(acc[m][n][r]);
}

// Flash attention on 32x32x16 MFMA. Grid 512 (16 q-tiles x 32 bh), 256 thr
// (4 waves x 32 q-rows). XCD remap: xcd = L&7 owns bh in [4*xcd, 4*xcd+4).
// LDS (u16): Ks [0,8192) [64][128] col-XOR-swizzled rows (256B, swz bits4-6);
//            Vs [8192,16384) subtiled [kt=k/4][dt=d/16][4][16];
//            PL [16384,24576) per-wave [32 q][64 k] bf16, XOR-swizzled.
// smaskF: f32[2048] additive mask. Q [128][128] staged in Ks+Vs pre-loop.
// Swapped QK^T: S^T = mfma32(Kfrag, Qfrag): lane owns q = lane&31;
// k rows = kb*32 + (reg&3) + 8*(reg>>2) + 4*(lane>>5). Softmax in-lane.
__global__ __launch_bounds__(256, 2) void attn_fused(
    const unsigned short* __restrict__ Qp, const unsigned short* __restrict__ Kp,
    const unsigned short* __restrict__ Vp, const int* __restrict__ mask,
    unsigned short* __restrict__ Att) {
  constexpr int DD = 1024, NK = 2048;
  __shared__ __align__(16) unsigned short lds[24576];
  __shared__ __align__(16) float smaskF[2048];
  unsigned short* Ks = lds;
  unsigned short* Vs = lds + 8192;

  const int tid = threadIdx.x, lane = tid & 63, w = tid >> 6;
  const int quad = lane >> 4, lq = lane & 15;
  const int hi = lane >> 5, q5 = lane & 31;
  const int L = blockIdx.x;
  const int bh = (L & 7) * 4 + (L >> 7);   // 4 heads per XCD
  const int qt = (L >> 3) & 15;
  const int b = bh >> 3, h = bh & 7;
  const int q0 = qt * 128;
  const unsigned short* Qbase = Qp + ((size_t)b * 2048 + q0) * DD + h * 128;
  const unsigned short* Kbase = Kp + (size_t)b * 2048 * DD + h * 128;
  const unsigned short* Vbase = Vp + (size_t)b * 2048 * DD + h * 128;
  char* PLw = (char*)(lds + 16384 + w * 2048);

  // ---- stage Q tile [128][128] (linear, Ks+Vs area) then hoist frags ----
#pragma unroll
  for (int j = 0; j < 8; ++j) {
    int row = w * 32 + j * 4 + quad;
    const unsigned short* g = Qbase + (size_t)row * DD + lq * 8;
    gload_lds16(g, lds + w * 4096 + j * 512);
  }
  asm volatile("s_waitcnt vmcnt(0)" ::: "memory");
  __syncthreads();
  // B-frag for mfma32: lane holds Q[q = q5 (+w*32)][d = ds*16 + hi*8 + j]
  s16x8 qf[8];
#pragma unroll
  for (int ds = 0; ds < 8; ++ds)
    qf[ds] = *(const s16x8*)(lds + (w * 32 + q5) * 128 + ds * 16 + hi * 8);

  // ---- preload full additive mask row -> smaskF ----
  {
    const int4* mp = (const int4*)(mask + b * NK);
    int4 m0 = mp[tid];
    int4 m1 = mp[tid + 256];
    f32x4 w0, w1;
    w0[0] = m0.x ? -1e30f : 0.f; w0[1] = m0.y ? -1e30f : 0.f;
    w0[2] = m0.z ? -1e30f : 0.f; w0[3] = m0.w ? -1e30f : 0.f;
    w1[0] = m1.x ? -1e30f : 0.f; w1[1] = m1.y ? -1e30f : 0.f;
    w1[2] = m1.z ? -1e30f : 0.f; w1[3] = m1.w ? -1e30f : 0.f;
    *(f32x4*)(smaskF + 4 * tid) = w0;
    *(f32x4*)(smaskF + 4 * (tid + 256)) = w1;
  }

  const unsigned vb0 = lds_off(Vs);
  const int swzq = (q5 & 7) << 4;

  f32x16 o[4] = {};
  float mrow = -1e30f, lrow = 0.f;

  for (int kt = 0; kt < NK / 64; ++kt) {
    const int k0 = kt * 64;
    __syncthreads();  // prior iteration's LDS reads done before overwrite
    // stage K [64][128] with XOR-swizzled SOURCE (linear LDS dest)
#pragma unroll
    for (int j = 0; j < 4; ++j) {
      int row = w * 16 + j * 4 + quad;
      int cb = lq * 16;                      // byte chunk within 256B row
      int cbs = cb ^ ((row & 7) << 4);       // involution on bits 4..6
      const unsigned short* g = Kbase + (size_t)(k0 + row) * DD + (cbs >> 1);
      gload_lds16(g, Ks + w * 2048 + j * 512);
    }
    // stage V into subtile layout [k/4][d/16][4][16] via pre-swizzled source
#pragma unroll
    for (int it = 0; it < 4; ++it) {
      int s = w * 256 + it * 64 + lane;
      int kk = ((s >> 6) << 2) | ((s >> 1) & 3);
      int dd = (((s >> 3) & 7) << 4) | ((s & 1) << 3);
      const unsigned short* g = Vbase + (size_t)(k0 + kk) * DD + dd;
      gload_lds16(g, Vs + (size_t)(w * 256 + it * 64) * 8);
    }
    asm volatile("s_waitcnt vmcnt(0)" ::: "memory");
    __syncthreads();

    // ---- S^T = (K Q^T)/32 + mask ----
    f32x16 acc0 = {}, acc1 = {};
    __builtin_amdgcn_s_setprio(1);
#pragma unroll
    for (int ds = 0; ds < 8; ++ds) {
      int cbs = (ds * 32 + hi * 16) ^ swzq;  // row&7 == q5&7 for both kb
      s16x8 kf0 = *(const s16x8*)((const char*)Ks + q5 * 256 + cbs);
      s16x8 kf1 = *(const s16x8*)((const char*)Ks + (q5 + 32) * 256 + cbs);
      acc0 = __builtin_amdgcn_mfma_f32_32x32x16_bf16(kf0, qf[ds], acc0, 0, 0, 0);
      acc1 = __builtin_amdgcn_mfma_f32_32x32x16_bf16(kf1, qf[ds], acc1, 0, 0, 0);
    }
    __builtin_amdgcn_s_setprio(0);

    // scale + mask; reg -> k = kb*32 + (reg&3) + 8*(reg>>2) + 4*hi
    float sv0[16], sv1[16];
#pragma unroll
    for (int g2 = 0; g2 < 4; ++g2) {
      f32x4 m0 = *(const f32x4*)(smaskF + k0 + g2 * 8 + hi * 4);
      f32x4 m1 = *(const f32x4*)(smaskF + k0 + 32 + g2 * 8 + hi * 4);
#pragma unroll
      for (int j2 = 0; j2 < 4; ++j2) {
        sv0[g2 * 4 + j2] = fmaf(acc0[g2 * 4 + j2], 0.03125f, m0[j2]);
        sv1[g2 * 4 + j2] = fmaf(acc1[g2 * 4 + j2], 0.03125f, m1[j2]);
      }
    }

    // ---- online softmax, in-lane over 32 values + one shfl ----
    float tm = fmaxf(sv0[0], sv1[0]);
#pragma unroll
    for (int r = 1; r < 16; ++r) tm = fmaxf(tm, fmaxf(sv0[r], sv1[r]));
    tm = fmaxf(tm, __shfl_xor(tm, 32, 64));
    // T13 defer-max
    const bool up = !__all(tm - mrow <= 8.f);
    float al = 1.f;
    if (up) {
      float mn = fmaxf(mrow, tm);
      al = __expf(mrow - mn);
      mrow = mn;
    }
    // P = exp(S - m) -> bf16 pack -> PL[q][k] (XOR-swizzled)
    float rs = 0.f;
#pragma unroll
    for (int g2 = 0; g2 < 4; ++g2) {
      {
        float p0 = __expf(sv0[g2 * 4 + 0] - mrow);
        float p1 = __expf(sv0[g2 * 4 + 1] - mrow);
        float p2 = __expf(sv0[g2 * 4 + 2] - mrow);
        float p3 = __expf(sv0[g2 * 4 + 3] - mrow);
        rs += (p0 + p1) + (p2 + p3);
        unsigned lo, hi2;
        asm("v_cvt_pk_bf16_f32 %0, %1, %2" : "=v"(lo) : "v"(p0), "v"(p1));
        asm("v_cvt_pk_bf16_f32 %0, %1, %2" : "=v"(hi2) : "v"(p2), "v"(p3));
        u32x2 pk; pk[0] = lo; pk[1] = hi2;
        *(u32x2*)(PLw + ((q5 * 128 + g2 * 16 + hi * 8) ^ swzq)) = pk;
      }
      {
        float p0 = __expf(sv1[g2 * 4 + 0] - mrow);
        float p1 = __expf(sv1[g2 * 4 + 1] - mrow);
        float p2 = __expf(sv1[g2 * 4 + 2] - mrow);
        float p3 = __expf(sv1[g2 * 4 + 3] - mrow);
        rs += (p0 + p1) + (p2 + p3);
        unsigned lo, hi2;
        asm("v_cvt_pk_bf16_f32 %0, %1, %2" : "=v"(lo) : "v"(p0), "v"(p1));
        asm("v_cvt_pk_bf16_f32 %0, %1, %2" : "=v"(hi2) : "v"(p2), "v"(p3));
        u32x2 pk; pk[0] = lo; pk[1] = hi2;
        *(u32x2*)(PLw + ((q5 * 128 + 64 + g2 * 16 + hi * 8) ^ swzq)) = pk;
      }
    }
    rs += __shfl_xor(rs, 32, 64);
    lrow = lrow * al + rs;
    if (up) {
#pragma unroll
      for (int reg = 0; reg < 16; ++reg) {
        float alo = __shfl(al, (reg & 3) + 8 * (reg >> 2) + 4 * hi, 64);
#pragma unroll
        for (int db = 0; db < 4; ++db) o[db][reg] *= alo;
      }
    }

    // ---- O += P V ----
    // pa hoisted: does NOT depend on db (was re-read 4x -> 4x PL traffic).
    s16x8 pa[4];
#pragma unroll
    for (int kb2 = 0; kb2 < 4; ++kb2)
      pa[kb2] = *(const s16x8*)(
          PLw + ((q5 * 128 + kb2 * 32 + hi * 16) ^ swzq));
#pragma unroll
    for (int db = 0; db < 4; ++db) {
      s16x4 vlo[4], vhi[4];
#pragma unroll
      for (int kb2 = 0; kb2 < 4; ++kb2) {
        const unsigned va = vb0 + (kb2 * 4 + hi * 2) * 1024 +
                            (db * 2 + (quad & 1)) * 128 + lq * 8;
        asm volatile("ds_read_b64_tr_b16 %0, %2\n\t"
                     "ds_read_b64_tr_b16 %1, %2 offset:1024"
                     : "=&v"(vlo[kb2]), "=&v"(vhi[kb2])
                     : "v"(va)
                     : "memory");
      }
      asm volatile("s_waitcnt lgkmcnt(0)" ::: "memory");
      __builtin_amdgcn_sched_barrier(0);
      __builtin_amdgcn_s_setprio(1);
#pragma unroll
      for (int kb2 = 0; kb2 < 4; ++kb2) {
        s16x8 vv;
#pragma unroll
        for (int j = 0; j < 4; ++j) { vv[j] = vlo[kb2][j]; vv[4 + j] = vhi[kb2][j]; }
        o[db] = __builtin_amdgcn_mfma_f32_32x32x16_bf16(pa[kb2], vv, o[db], 0, 0, 0);
      }
      __builtin_amdgcn_s_setprio(0);
    }
  }

  // ---- normalize + write ----
  float inv = (mrow <= -1e29f || lrow <= 0.f) ? 0.f : 1.f / lrow;
#pragma unroll
  for (int reg = 0; reg < 16; ++reg) {
    const int rown = (reg & 3) + 8 * (reg >> 2) + 4 * hi;
    float invo = __shfl(inv, rown, 64);
    const int q = q0 + w * 32 + rown;
#pragma unroll
    for (int db = 0; db < 4; ++db) {
      Att[((size_t)b * 2048 + q) * DD + h * 128 + db * 32 + q5] =
          f2bf(o[db][reg] * invo);
    }
  }
}

// out = LayerNorm(X + Y) * g + b. One block per 1024-elem row.
template<int OUT_F32>
__global__ __launch_bounds__(256) void add_ln(
    const unsigned short* __restrict__ X, const unsigned short* __restrict__ Y,
    const float* __restrict__ gam, const float* __restrict__ bet,
    void* __restrict__ out) {
  const int row = blockIdx.x;
  const int tid = threadIdx.x;
  const int lane = tid & 63, w = tid >> 6;
  __shared__ float rbuf[8];
  const size_t base = (size_t)row * 1024 + tid * 4;
  s16x4 xa = *(const s16x4*)(X + base);
  s16x4 yb = *(const s16x4*)(Y + base);
  float x[4];
  float s1 = 0.f, s2 = 0.f;
#pragma unroll
  for (int j = 0; j < 4; ++j) {
    x[j] = bf2f((unsigned short)xa[j]) + bf2f((unsigned short)yb[j]);
    s1 += x[j];
    s2 += x[j] * x[j];
  }
#pragma unroll
  for (int d = 1; d < 64; d <<= 1) {
    s1 += __shfl_xor(s1, d, 64);
    s2 += __shfl_xor(s2, d, 64);
  }
  if (lane == 0) { rbuf[w] = s1; rbuf[4 + w] = s2; }
  __syncthreads();
  float t1 = rbuf[0] + rbuf[1] + rbuf[2] + rbuf[3];
  float t2 = rbuf[4] + rbuf[5] + rbuf[6] + rbuf[7];
  float mu = t1 * (1.f / 1024.f);
  float var = t2 * (1.f / 1024.f) - mu * mu;
  float rstd = rsqrtf(fmaxf(var, 0.f) + 1e-5f);
  float4 g4 = *(const float4*)(gam + tid * 4);
  float4 b4 = *(const float4*)(bet + tid * 4);
  float gg[4] = {g4.x, g4.y, g4.z, g4.w};
  float bb[4] = {b4.x, b4.y, b4.z, b4.w};
  if (OUT_F32) {
    float4 o4;
    o4.x = (x[0] - mu) * rstd * gg[0] + bb[0];
    o4.y = (x[1] - mu) * rstd * gg[1] + bb[1];
    o4.z = (x[2] - mu) * rstd * gg[2] + bb[2];
    o4.w = (x[3] - mu) * rstd * gg[3] + bb[3];
    *(float4*)((float*)out + base) = o4;
  } else {
    s16x4 o;
#pragma unroll
    for (int j = 0; j < 4; ++j)
      o[j] = (short)f2bf((x[j] - mu) * rstd * gg[j] + bb[j]);
    *(s16x4*)((unsigned short*)out + base) = o;
  }
}

extern "C" void kernel_launch(void* const* d_in, const int* in_sizes, int n_in,
                              void* d_out, int out_size, void* d_ws, size_t ws_size,
                              hipStream_t stream) {
  const float* q  = (const float*)d_in[0];
  const float* k  = (const float*)d_in[1];
  const float* v  = (const float*)d_in[2];
  const int* msk  = (const int*)d_in[3];
  const float* Wq = (const float*)d_in[4];
  const float* Wk = (const float*)d_in[5];
  const float* Wv = (const float*)d_in[6];
  const float* Wo = (const float*)d_in[7];
  const float* bo = (const float*)d_in[8];
  const float* g1 = (const float*)d_in[9];
  const float* b1 = (const float*)d_in[10];
  const float* g2 = (const float*)d_in[11];
  const float* b2 = (const float*)d_in[12];
  float* out = (float*)d_out;

  char* ws = (char*)d_ws;
  const size_t S = (size_t)8192 * 1024 * 2;
  unsigned short* qb  = (unsigned short*)(ws + 0 * S);
  unsigned short* kb  = (unsigned short*)(ws + 1 * S);
  unsigned short* vb  = (unsigned short*)(ws + 2 * S);
  unsigned short* qpb = (unsigned short*)(ws + 3 * S);
  unsigned short* kpb = (unsigned short*)(ws + 4 * S);
  unsigned short* vpb = (unsigned short*)(ws + 5 * S);
  unsigned short* attb = qb;  // reuse: q bf16 dead after proj
  unsigned short* h1b  = kb;
  unsigned short* h2b  = vb;
  unsigned short* Wqb = (unsigned short*)(ws + 6 * S);
  unsigned short* Wkb = Wqb + (size_t)1024 * 1024;
  unsigned short* Wvb = Wkb + (size_t)1024 * 1024;
  unsigned short* Wob = Wvb + (size_t)1024 * 1024;

  const int n4big = 8192 * 1024 / 4;
  const int n4w   = 1024 * 1024 / 4;
  cvt_multi<<<dim3(8192, 3), 256, 0, stream>>>(q, k, v, v, qb, kb, vb, vb, n4big);
  cvt_multi<<<dim3(1024, 4), 256, 0, stream>>>(Wq, Wk, Wv, Wo, Wqb, Wkb, Wvb, Wob, n4w);

  gemm_proj3<<<dim3(64, 8, 3), 256, 0, stream>>>(
      qb, kb, vb, Wqb, Wkb, Wvb, qpb, kpb, vpb, 8192, 1024, 1024);

  attn_fused<<<512, 256, 0, stream>>>(qpb, kpb, vpb, msk, attb);

  add_ln<0><<<8192, 256, 0, stream>>>(qpb, attb, g1, b1, (void*)h1b);
  gemm_bt<1><<<dim3(64, 8), 256, 0, stream>>>(h1b, Wob, h2b, bo, 8192, 1024, 1024);
  add_ln<1><<<8192, 256, 0, stream>>>(h1b, h2b, g2, b2, (void*)out);
}